// Round 1
// baseline (5862.444 us; speedup 1.0000x reference)
//
#include <hip/hip_runtime.h>

#define NN 100000
#define D 128

__device__ __forceinline__ float4 ld4(const float* p) { return *(const float4*)p; }

// out[r][c] = act( sum_k (A1[r][k] (+A2[r][k])) * W[k][c] + bias[c] (+ res[r][c]) )
// Block: 256 threads, tile 64 rows x 128 cols, microtile 4x8.
// A staged transposed in LDS; W read from global (L1/L2 resident, 64KB).
template<bool HAS_A2, bool HAS_RES, bool RELU>
__global__ __launch_bounds__(256) void gemm128(
    const float* __restrict__ A1, const float* __restrict__ A2,
    const float* __restrict__ W, const float* __restrict__ bias,
    const float* res, float* out, int N)
{
    __shared__ float xT[D][65];   // [k][row], odd row-stride to soften write conflicts
    const int t  = threadIdx.x;
    const int r0 = blockIdx.x * 64;

    // ---- stage A (64 rows x 128 cols) transposed into LDS ----
    {
        const int lr = t >> 5;          // 0..7
        const int lc = (t & 31) << 2;   // 0,4,...,124
        #pragma unroll
        for (int p = 0; p < 8; ++p) {
            const int row = p * 8 + lr;
            const int gr  = r0 + row;
            float4 v = make_float4(0.f, 0.f, 0.f, 0.f);
            if (gr < N) {
                v = ld4(&A1[gr * D + lc]);
                if (HAS_A2) {
                    float4 v2 = ld4(&A2[gr * D + lc]);
                    v.x += v2.x; v.y += v2.y; v.z += v2.z; v.w += v2.w;
                }
            }
            xT[lc + 0][row] = v.x;
            xT[lc + 1][row] = v.y;
            xT[lc + 2][row] = v.z;
            xT[lc + 3][row] = v.w;
        }
    }
    __syncthreads();

    const int tx = t & 15;    // col group: cols tx*8 .. tx*8+7
    const int ty = t >> 4;    // row group: rows ty*4 .. ty*4+3
    const int cb = tx * 8;
    const int rb = ty * 4;

    float acc[4][8];
    #pragma unroll
    for (int i = 0; i < 4; ++i)
        #pragma unroll
        for (int j = 0; j < 8; ++j)
            acc[i][j] = 0.f;

    #pragma unroll 8
    for (int k = 0; k < D; ++k) {
        float a[4];
        #pragma unroll
        for (int i = 0; i < 4; ++i) a[i] = xT[k][rb + i];
        const float4 w0 = ld4(&W[k * D + cb]);
        const float4 w1 = ld4(&W[k * D + cb + 4]);
        const float w[8] = { w0.x, w0.y, w0.z, w0.w, w1.x, w1.y, w1.z, w1.w };
        #pragma unroll
        for (int i = 0; i < 4; ++i)
            #pragma unroll
            for (int j = 0; j < 8; ++j)
                acc[i][j] += a[i] * w[j];
    }

    // ---- epilogue ----
    const float4 b0 = ld4(&bias[cb]);
    const float4 b1 = ld4(&bias[cb + 4]);
    const float bb[8] = { b0.x, b0.y, b0.z, b0.w, b1.x, b1.y, b1.z, b1.w };

    #pragma unroll
    for (int i = 0; i < 4; ++i) {
        const int gr = r0 + rb + i;
        if (gr >= N) continue;
        float o[8];
        #pragma unroll
        for (int j = 0; j < 8; ++j) o[j] = acc[i][j] + bb[j];
        if (HAS_RES) {
            const float4 rv0 = ld4(&res[gr * D + cb]);
            const float4 rv1 = ld4(&res[gr * D + cb + 4]);
            o[0] += rv0.x; o[1] += rv0.y; o[2] += rv0.z; o[3] += rv0.w;
            o[4] += rv1.x; o[5] += rv1.y; o[6] += rv1.z; o[7] += rv1.w;
        }
        if (RELU) {
            #pragma unroll
            for (int j = 0; j < 8; ++j) o[j] = fmaxf(o[j], 0.f);
        }
        *(float4*)&out[gr * D + cb]     = make_float4(o[0], o[1], o[2], o[3]);
        *(float4*)&out[gr * D + cb + 4] = make_float4(o[4], o[5], o[6], o[7]);
    }
}

// message + scatter-add: m = relu(h[src] + emb[attr]); agg[dst] += m
// 32 threads per edge, 4 floats each (float4, coalesced 512B per edge).
__global__ __launch_bounds__(256) void edge_msg(
    const float* __restrict__ h, const int* __restrict__ src,
    const int* __restrict__ dst, const int* __restrict__ attr,
    const float* __restrict__ emb, float* agg, int E)
{
    const long long gt = (long long)blockIdx.x * 256 + threadIdx.x;
    const int e = (int)(gt >> 5);
    if (e >= E) return;
    const int c = ((int)gt & 31) << 2;

    const int s = src[e];
    const int d = dst[e];
    const int a = attr[e];

    const float4 hv = ld4(&h[s * D + c]);
    const float4 ev = ld4(&emb[a * D + c]);
    const float m0 = fmaxf(hv.x + ev.x, 0.f);
    const float m1 = fmaxf(hv.y + ev.y, 0.f);
    const float m2 = fmaxf(hv.z + ev.z, 0.f);
    const float m3 = fmaxf(hv.w + ev.w, 0.f);

    float* p = &agg[d * D + c];
    atomicAdd(p + 0, m0);
    atomicAdd(p + 1, m1);
    atomicAdd(p + 2, m2);
    atomicAdd(p + 3, m3);
}

// out[r] = dot(h[r], Wout) + b_out ; 4 lanes per row
__global__ __launch_bounds__(256) void out_proj(
    const float* __restrict__ h, const float* __restrict__ Wout,
    const float* __restrict__ bout, float* __restrict__ out, int N)
{
    const int gt = blockIdx.x * 256 + threadIdx.x;
    const int r = gt >> 2;
    if (r >= N) return;
    const int q = gt & 3;

    const float* hr = &h[r * D + q * 32];
    const float* wr = &Wout[q * 32];
    float acc = 0.f;
    #pragma unroll
    for (int k = 0; k < 32; k += 4) {
        const float4 hv = ld4(hr + k);
        const float4 wv = ld4(wr + k);
        acc += hv.x * wv.x + hv.y * wv.y + hv.z * wv.z + hv.w * wv.w;
    }
    acc += __shfl_xor(acc, 1);
    acc += __shfl_xor(acc, 2);
    if (q == 0) out[r] = acc + bout[0];
}

extern "C" void kernel_launch(void* const* d_in, const int* in_sizes, int n_in,
                              void* d_out, int out_size, void* d_ws, size_t ws_size,
                              hipStream_t stream)
{
    const float* x     = (const float*)d_in[0];
    const int*   ei    = (const int*)  d_in[1];
    const int*   attr  = (const int*)  d_in[2];
    const float* emb   = (const float*)d_in[3];
    const float* Win   = (const float*)d_in[4];
    const float* b_in  = (const float*)d_in[5];
    const float* W1_0  = (const float*)d_in[6];
    const float* b1_0  = (const float*)d_in[7];
    const float* W2_0  = (const float*)d_in[8];
    const float* b2_0  = (const float*)d_in[9];
    const float* W1_1  = (const float*)d_in[10];
    const float* b1_1  = (const float*)d_in[11];
    const float* W2_1  = (const float*)d_in[12];
    const float* b2_1  = (const float*)d_in[13];
    const float* Wout  = (const float*)d_in[14];
    const float* b_out = (const float*)d_in[15];
    float* out = (float*)d_out;

    const int N = NN;
    const int E = in_sizes[2];        // edge_attr count == number of edges
    const int* srcp = ei;             // edge_index[0]
    const int* dstp = ei + E;         // edge_index[1]

    float* h   = (float*)d_ws;                 // N*D floats
    float* agg = h + (size_t)N * D;            // N*D floats

    dim3 blk(256);
    const int ggrid = (N + 63) / 64;

    // h = x @ Win + b_in
    gemm128<false, false, false><<<ggrid, blk, 0, stream>>>(x, nullptr, Win, b_in, nullptr, h, N);

    for (int l = 0; l < 2; ++l) {
        const float* W1 = l ? W1_1 : W1_0;
        const float* b1 = l ? b1_1 : b1_0;
        const float* W2 = l ? W2_1 : W2_0;
        const float* b2 = l ? b2_1 : b2_0;

        hipMemsetAsync(agg, 0, (size_t)N * D * sizeof(float), stream);
        const int eg = (int)(((long long)E * 32 + 255) / 256);
        edge_msg<<<eg, blk, 0, stream>>>(h, srcp, dstp, attr, emb, agg, E);

        // u = relu((agg + h) @ W1 + b1)   (in-place into agg: safe, row-local)
        gemm128<true, false, true><<<ggrid, blk, 0, stream>>>(agg, h, W1, b1, nullptr, agg, N);
        // h = relu(u @ W2 + b2 + h)       (in-place into h: row-local)
        gemm128<false, true, true><<<ggrid, blk, 0, stream>>>(agg, nullptr, W2, b2, h, h, N);
    }

    out_proj<<<(N * 4 + 255) / 256, blk, 0, stream>>>(h, Wout, b_out, out, N);
}

// Round 2
// 892.872 us; speedup vs baseline: 6.5658x; 6.5658x over previous
//
#include <hip/hip_runtime.h>

#define NN 100000
#define D 128

__device__ __forceinline__ float4 ld4(const float* p) { return *(const float4*)p; }

// ---------------- GEMM (unchanged from R0) ----------------
template<bool HAS_A2, bool HAS_RES, bool RELU>
__global__ __launch_bounds__(256) void gemm128(
    const float* __restrict__ A1, const float* __restrict__ A2,
    const float* __restrict__ W, const float* __restrict__ bias,
    const float* res, float* out, int N)
{
    __shared__ float xT[D][65];
    const int t  = threadIdx.x;
    const int r0 = blockIdx.x * 64;

    {
        const int lr = t >> 5;
        const int lc = (t & 31) << 2;
        #pragma unroll
        for (int p = 0; p < 8; ++p) {
            const int row = p * 8 + lr;
            const int gr  = r0 + row;
            float4 v = make_float4(0.f, 0.f, 0.f, 0.f);
            if (gr < N) {
                v = ld4(&A1[gr * D + lc]);
                if (HAS_A2) {
                    float4 v2 = ld4(&A2[gr * D + lc]);
                    v.x += v2.x; v.y += v2.y; v.z += v2.z; v.w += v2.w;
                }
            }
            xT[lc + 0][row] = v.x;
            xT[lc + 1][row] = v.y;
            xT[lc + 2][row] = v.z;
            xT[lc + 3][row] = v.w;
        }
    }
    __syncthreads();

    const int tx = t & 15;
    const int ty = t >> 4;
    const int cb = tx * 8;
    const int rb = ty * 4;

    float acc[4][8];
    #pragma unroll
    for (int i = 0; i < 4; ++i)
        #pragma unroll
        for (int j = 0; j < 8; ++j)
            acc[i][j] = 0.f;

    #pragma unroll 8
    for (int k = 0; k < D; ++k) {
        float a[4];
        #pragma unroll
        for (int i = 0; i < 4; ++i) a[i] = xT[k][rb + i];
        const float4 w0 = ld4(&W[k * D + cb]);
        const float4 w1 = ld4(&W[k * D + cb + 4]);
        const float w[8] = { w0.x, w0.y, w0.z, w0.w, w1.x, w1.y, w1.z, w1.w };
        #pragma unroll
        for (int i = 0; i < 4; ++i)
            #pragma unroll
            for (int j = 0; j < 8; ++j)
                acc[i][j] += a[i] * w[j];
    }

    const float4 b0 = ld4(&bias[cb]);
    const float4 b1 = ld4(&bias[cb + 4]);
    const float bb[8] = { b0.x, b0.y, b0.z, b0.w, b1.x, b1.y, b1.z, b1.w };

    #pragma unroll
    for (int i = 0; i < 4; ++i) {
        const int gr = r0 + rb + i;
        if (gr >= N) continue;
        float o[8];
        #pragma unroll
        for (int j = 0; j < 8; ++j) o[j] = acc[i][j] + bb[j];
        if (HAS_RES) {
            const float4 rv0 = ld4(&res[gr * D + cb]);
            const float4 rv1 = ld4(&res[gr * D + cb + 4]);
            o[0] += rv0.x; o[1] += rv0.y; o[2] += rv0.z; o[3] += rv0.w;
            o[4] += rv1.x; o[5] += rv1.y; o[6] += rv1.z; o[7] += rv1.w;
        }
        if (RELU) {
            #pragma unroll
            for (int j = 0; j < 8; ++j) o[j] = fmaxf(o[j], 0.f);
        }
        *(float4*)&out[gr * D + cb]     = make_float4(o[0], o[1], o[2], o[3]);
        *(float4*)&out[gr * D + cb + 4] = make_float4(o[4], o[5], o[6], o[7]);
    }
}

// ---------------- CSR build ----------------
__global__ __launch_bounds__(256) void hist_kernel(
    const int* __restrict__ dst, int* __restrict__ deg, int E)
{
    const int e = blockIdx.x * 256 + threadIdx.x;
    if (e < E) atomicAdd(&deg[dst[e]], 1);
}

// block sums of deg (256 per block)
__global__ __launch_bounds__(256) void scan_bsum(
    const int* __restrict__ deg, int* __restrict__ bsum, int n)
{
    __shared__ int s[256];
    const int t = threadIdx.x;
    const int i = blockIdx.x * 256 + t;
    s[t] = (i < n) ? deg[i] : 0;
    __syncthreads();
    for (int off = 128; off > 0; off >>= 1) {
        if (t < off) s[t] += s[t + off];
        __syncthreads();
    }
    if (t == 0) bsum[blockIdx.x] = s[0];
}

// single-block exclusive scan of nb (<=512) block sums
__global__ __launch_bounds__(512) void scan_small(
    const int* __restrict__ bsum, int* __restrict__ boff, int nb)
{
    __shared__ int s[512];
    const int t = threadIdx.x;
    const int v = (t < nb) ? bsum[t] : 0;
    s[t] = v;
    __syncthreads();
    for (int off = 1; off < 512; off <<= 1) {
        const int x = (t >= off) ? s[t - off] : 0;
        __syncthreads();
        s[t] += x;
        __syncthreads();
    }
    if (t < nb) boff[t] = s[t] - v;   // exclusive
}

// per-block exclusive scan + block offset -> rowptr[i] = sum deg[0..i-1]
__global__ __launch_bounds__(256) void scan_final(
    const int* __restrict__ deg, const int* __restrict__ boff,
    int* __restrict__ rowptr, int n)
{
    __shared__ int s[256];
    const int t = threadIdx.x;
    const int i = blockIdx.x * 256 + t;
    const int v = (i < n) ? deg[i] : 0;
    s[t] = v;
    __syncthreads();
    for (int off = 1; off < 256; off <<= 1) {
        const int x = (t >= off) ? s[t - off] : 0;
        __syncthreads();
        s[t] += x;
        __syncthreads();
    }
    if (i < n) rowptr[i] = boff[blockIdx.x] + s[t] - v;
}

// scatter: epack[pos] = src | (attr<<20); converts rowptr into END offsets
__global__ __launch_bounds__(256) void scatter_kernel(
    const int* __restrict__ src, const int* __restrict__ dst,
    const int* __restrict__ attr, int* __restrict__ rowptr,
    int* __restrict__ epack, int E)
{
    const int e = blockIdx.x * 256 + threadIdx.x;
    if (e >= E) return;
    const int p = atomicAdd(&rowptr[dst[e]], 1);
    epack[p] = src[e] | (attr[e] << 20);
}

// ---------------- CSR aggregate: one wave per node ----------------
// agg[n] = sum_{j in edges(n)} relu(h[src_j] + emb[attr_j])
// rowptr holds END offsets (post-scatter); start = rowptr[n-1] (0 for n=0).
__global__ __launch_bounds__(256) void aggregate(
    const float* __restrict__ h, const int* __restrict__ rowptr,
    const int* __restrict__ epack, const float* __restrict__ emb,
    float* __restrict__ agg, int N)
{
    const int node = blockIdx.x * 4 + (threadIdx.x >> 6);
    const int lane = threadIdx.x & 63;
    if (node >= N) return;

    int start = (node == 0) ? 0 : rowptr[node - 1];
    int end   = rowptr[node];
    start = __builtin_amdgcn_readfirstlane(start);
    end   = __builtin_amdgcn_readfirstlane(end);

    const float2* __restrict__ h2 = (const float2*)h;
    const float2* __restrict__ e2 = (const float2*)emb;

    float ax = 0.f, ay = 0.f;
    int j = start;
    for (; j + 1 < end; j += 2) {
        const int p0 = __builtin_amdgcn_readfirstlane(epack[j]);
        const int p1 = __builtin_amdgcn_readfirstlane(epack[j + 1]);
        const int s0 = p0 & 0xFFFFF, a0 = p0 >> 20;
        const int s1 = p1 & 0xFFFFF, a1 = p1 >> 20;
        const float2 h0 = h2[s0 * 64 + lane];
        const float2 h1 = h2[s1 * 64 + lane];
        const float2 e0 = e2[a0 * 64 + lane];
        const float2 e1 = e2[a1 * 64 + lane];
        ax += fmaxf(h0.x + e0.x, 0.f) + fmaxf(h1.x + e1.x, 0.f);
        ay += fmaxf(h0.y + e0.y, 0.f) + fmaxf(h1.y + e1.y, 0.f);
    }
    if (j < end) {
        const int p0 = __builtin_amdgcn_readfirstlane(epack[j]);
        const int s0 = p0 & 0xFFFFF, a0 = p0 >> 20;
        const float2 h0 = h2[s0 * 64 + lane];
        const float2 e0 = e2[a0 * 64 + lane];
        ax += fmaxf(h0.x + e0.x, 0.f);
        ay += fmaxf(h0.y + e0.y, 0.f);
    }
    float2 o; o.x = ax; o.y = ay;
    ((float2*)agg)[node * 64 + lane] = o;
}

// ---------------- output projection ----------------
__global__ __launch_bounds__(256) void out_proj(
    const float* __restrict__ h, const float* __restrict__ Wout,
    const float* __restrict__ bout, float* __restrict__ out, int N)
{
    const int gt = blockIdx.x * 256 + threadIdx.x;
    const int r = gt >> 2;
    if (r >= N) return;
    const int q = gt & 3;

    const float* hr = &h[r * D + q * 32];
    const float* wr = &Wout[q * 32];
    float acc = 0.f;
    #pragma unroll
    for (int k = 0; k < 32; k += 4) {
        const float4 hv = ld4(hr + k);
        const float4 wv = ld4(wr + k);
        acc += hv.x * wv.x + hv.y * wv.y + hv.z * wv.z + hv.w * wv.w;
    }
    acc += __shfl_xor(acc, 1);
    acc += __shfl_xor(acc, 2);
    if (q == 0) out[r] = acc + bout[0];
}

extern "C" void kernel_launch(void* const* d_in, const int* in_sizes, int n_in,
                              void* d_out, int out_size, void* d_ws, size_t ws_size,
                              hipStream_t stream)
{
    const float* x     = (const float*)d_in[0];
    const int*   ei    = (const int*)  d_in[1];
    const int*   attr  = (const int*)  d_in[2];
    const float* emb   = (const float*)d_in[3];
    const float* Win   = (const float*)d_in[4];
    const float* b_in  = (const float*)d_in[5];
    const float* W1_0  = (const float*)d_in[6];
    const float* b1_0  = (const float*)d_in[7];
    const float* W2_0  = (const float*)d_in[8];
    const float* b2_0  = (const float*)d_in[9];
    const float* W1_1  = (const float*)d_in[10];
    const float* b1_1  = (const float*)d_in[11];
    const float* W2_1  = (const float*)d_in[12];
    const float* b2_1  = (const float*)d_in[13];
    const float* Wout  = (const float*)d_in[14];
    const float* b_out = (const float*)d_in[15];
    float* out = (float*)d_out;

    const int N = NN;
    const int E = in_sizes[2];
    const int* srcp = ei;
    const int* dstp = ei + E;

    // workspace layout
    float* h      = (float*)d_ws;                    // N*D
    float* agg    = h + (size_t)N * D;               // N*D
    int*   deg    = (int*)(agg + (size_t)N * D);     // N
    int*   rowptr = deg + N;                         // N
    int*   epack  = rowptr + N;                      // E
    int*   bsum   = epack + E;                       // <=512
    int*   boff   = bsum + 512;                      // <=512

    dim3 blk(256);
    const int nb    = (N + 255) / 256;               // 391 scan blocks
    const int eg    = (E + 255) / 256;
    const int ggrid = (N + 63) / 64;

    // ---- CSR build (once; reused by both layers) ----
    hipMemsetAsync(deg, 0, (size_t)N * sizeof(int), stream);
    hist_kernel<<<eg, blk, 0, stream>>>(dstp, deg, E);
    scan_bsum<<<nb, blk, 0, stream>>>(deg, bsum, N);
    scan_small<<<1, 512, 0, stream>>>(bsum, boff, nb);
    scan_final<<<nb, blk, 0, stream>>>(deg, boff, rowptr, N);
    scatter_kernel<<<eg, blk, 0, stream>>>(srcp, dstp, attr, rowptr, epack, E);

    // ---- h = x @ Win + b_in ----
    gemm128<false, false, false><<<ggrid, blk, 0, stream>>>(x, nullptr, Win, b_in, nullptr, h, N);

    for (int l = 0; l < 2; ++l) {
        const float* W1 = l ? W1_1 : W1_0;
        const float* b1 = l ? b1_1 : b1_0;
        const float* W2 = l ? W2_1 : W2_0;
        const float* b2 = l ? b2_1 : b2_0;

        aggregate<<<(N + 3) / 4, blk, 0, stream>>>(h, rowptr, epack, emb, agg, N);
        // u = relu((agg + h) @ W1 + b1)   (in-place into agg: row-local)
        gemm128<true, false, true><<<ggrid, blk, 0, stream>>>(agg, h, W1, b1, nullptr, agg, N);
        // h = relu(u @ W2 + b2 + h)       (in-place into h: row-local)
        gemm128<false, true, true><<<ggrid, blk, 0, stream>>>(agg, nullptr, W2, b2, h, h, N);
    }

    out_proj<<<(N * 4 + 255) / 256, blk, 0, stream>>>(h, Wout, b_out, out, N);
}

// Round 3
// 836.598 us; speedup vs baseline: 7.0075x; 1.0673x over previous
//
#include <hip/hip_runtime.h>

#define NN 100000
#define D 128

typedef __attribute__((ext_vector_type(8))) short short8;
typedef __attribute__((ext_vector_type(4))) float f32x4;

__device__ __forceinline__ float4 ld4(const float* p) { return *(const float4*)p; }

__device__ __forceinline__ unsigned short f2bf(float f) {
    unsigned int u = __float_as_uint(f);
    unsigned int r = u + 0x7fffu + ((u >> 16) & 1u);   // RNE
    return (unsigned short)(r >> 16);
}
__device__ __forceinline__ float bf2f(unsigned short h) {
    return __uint_as_float(((unsigned int)h) << 16);
}

// ---------------- W prepack: fragment-ordered hi/lo bf16 ----------------
// Wp[((nt*4+ks)*64+L)*8+j] = W[ks*32 + (L>>4)*8 + j][nt*16 + (L&15)]
__global__ __launch_bounds__(256) void prepack_w(
    const float* __restrict__ W, unsigned short* __restrict__ hi,
    unsigned short* __restrict__ lo)
{
    const int t = blockIdx.x * 256 + threadIdx.x;
    if (t >= D * D) return;
    const int j  = t & 7;
    const int L  = (t >> 3) & 63;
    const int ks = (t >> 9) & 3;
    const int nt = t >> 11;
    const float v = W[(ks * 32 + (L >> 4) * 8 + j) * D + nt * 16 + (L & 15)];
    const unsigned short h = f2bf(v);
    hi[t] = h;
    lo[t] = f2bf(v - bf2f(h));
}

// ---------------- split-bf16 MFMA GEMM ----------------
// out[r][:] = act( (A1[r] (+A2[r])) @ W + bias (+ res[r]) ), D=128
// block = 256 thr (4 waves), 128 rows/block, wave = 32 rows x 128 cols
template<bool HAS_A2, bool HAS_RES, bool RELU>
__global__ __launch_bounds__(256) void gemm_mfma(
    const float* __restrict__ A1, const float* __restrict__ A2,
    const unsigned short* __restrict__ Whi, const unsigned short* __restrict__ Wlo,
    const float* __restrict__ bias, const float* res, float* out, int N)
{
    const int t  = threadIdx.x;
    const int wv = t >> 6;
    const int L  = t & 63;
    const int lr = L & 15;
    const int q  = L >> 4;
    const int m0 = blockIdx.x * 128 + wv * 32;

    f32x4 acc[2][8];
    #pragma unroll
    for (int mi = 0; mi < 2; ++mi)
        #pragma unroll
        for (int nt = 0; nt < 8; ++nt)
            acc[mi][nt] = (f32x4){0.f, 0.f, 0.f, 0.f};

    #pragma unroll
    for (int ks = 0; ks < 4; ++ks) {
        short8 ahi[2], alo[2];
        #pragma unroll
        for (int mi = 0; mi < 2; ++mi) {
            const int row = m0 + mi * 16 + lr;
            float v[8];
            if (row < N) {
                const float* p = &A1[row * D + ks * 32 + q * 8];
                const float4 x0 = ld4(p), x1 = ld4(p + 4);
                v[0] = x0.x; v[1] = x0.y; v[2] = x0.z; v[3] = x0.w;
                v[4] = x1.x; v[5] = x1.y; v[6] = x1.z; v[7] = x1.w;
                if (HAS_A2) {
                    const float* p2 = &A2[row * D + ks * 32 + q * 8];
                    const float4 y0 = ld4(p2), y1 = ld4(p2 + 4);
                    v[0] += y0.x; v[1] += y0.y; v[2] += y0.z; v[3] += y0.w;
                    v[4] += y1.x; v[5] += y1.y; v[6] += y1.z; v[7] += y1.w;
                }
            } else {
                #pragma unroll
                for (int j = 0; j < 8; ++j) v[j] = 0.f;
            }
            #pragma unroll
            for (int j = 0; j < 8; ++j) {
                const unsigned short h = f2bf(v[j]);
                ahi[mi][j] = (short)h;
                alo[mi][j] = (short)f2bf(v[j] - bf2f(h));
            }
        }
        #pragma unroll
        for (int nt = 0; nt < 8; ++nt) {
            const int base = ((nt * 4 + ks) * 64 + L) * 8;
            const short8 bhi = *(const short8*)&Whi[base];
            const short8 blo = *(const short8*)&Wlo[base];
            #pragma unroll
            for (int mi = 0; mi < 2; ++mi) {
                acc[mi][nt] = __builtin_amdgcn_mfma_f32_16x16x32_bf16(alo[mi], bhi, acc[mi][nt], 0, 0, 0);
                acc[mi][nt] = __builtin_amdgcn_mfma_f32_16x16x32_bf16(ahi[mi], blo, acc[mi][nt], 0, 0, 0);
                acc[mi][nt] = __builtin_amdgcn_mfma_f32_16x16x32_bf16(ahi[mi], bhi, acc[mi][nt], 0, 0, 0);
            }
        }
    }

    // ---- epilogue ----
    #pragma unroll
    for (int nt = 0; nt < 8; ++nt) {
        const float b = bias[nt * 16 + lr];
        #pragma unroll
        for (int mi = 0; mi < 2; ++mi) {
            #pragma unroll
            for (int r = 0; r < 4; ++r) {
                const int grow = m0 + mi * 16 + q * 4 + r;
                if (grow < N) {
                    float o = acc[mi][nt][r] + b;
                    if (HAS_RES) o += res[grow * D + nt * 16 + lr];
                    if (RELU)    o = fmaxf(o, 0.f);
                    out[grow * D + nt * 16 + lr] = o;
                }
            }
        }
    }
}

// ---------------- CSR build ----------------
__global__ __launch_bounds__(256) void hist_kernel(
    const int* __restrict__ dst, int* __restrict__ deg, int E)
{
    const int e = blockIdx.x * 256 + threadIdx.x;
    if (e < E) atomicAdd(&deg[dst[e]], 1);
}

__global__ __launch_bounds__(256) void scan_bsum(
    const int* __restrict__ deg, int* __restrict__ bsum, int n)
{
    __shared__ int s[256];
    const int t = threadIdx.x;
    const int i = blockIdx.x * 256 + t;
    s[t] = (i < n) ? deg[i] : 0;
    __syncthreads();
    for (int off = 128; off > 0; off >>= 1) {
        if (t < off) s[t] += s[t + off];
        __syncthreads();
    }
    if (t == 0) bsum[blockIdx.x] = s[0];
}

__global__ __launch_bounds__(512) void scan_small(
    const int* __restrict__ bsum, int* __restrict__ boff, int nb)
{
    __shared__ int s[512];
    const int t = threadIdx.x;
    const int v = (t < nb) ? bsum[t] : 0;
    s[t] = v;
    __syncthreads();
    for (int off = 1; off < 512; off <<= 1) {
        const int x = (t >= off) ? s[t - off] : 0;
        __syncthreads();
        s[t] += x;
        __syncthreads();
    }
    if (t < nb) boff[t] = s[t] - v;
}

__global__ __launch_bounds__(256) void scan_final(
    const int* __restrict__ deg, const int* __restrict__ boff,
    int* __restrict__ rowptr, int n)
{
    __shared__ int s[256];
    const int t = threadIdx.x;
    const int i = blockIdx.x * 256 + t;
    const int v = (i < n) ? deg[i] : 0;
    s[t] = v;
    __syncthreads();
    for (int off = 1; off < 256; off <<= 1) {
        const int x = (t >= off) ? s[t - off] : 0;
        __syncthreads();
        s[t] += x;
        __syncthreads();
    }
    if (i < n) rowptr[i] = boff[blockIdx.x] + s[t] - v;
}

__global__ __launch_bounds__(256) void scatter_kernel(
    const int* __restrict__ src, const int* __restrict__ dst,
    const int* __restrict__ attr, int* __restrict__ rowptr,
    int* __restrict__ epack, int E)
{
    const int e = blockIdx.x * 256 + threadIdx.x;
    if (e >= E) return;
    const int p = atomicAdd(&rowptr[dst[e]], 1);
    epack[p] = src[e] | (attr[e] << 20);
}

// ---------------- CSR aggregate: one wave per node ----------------
__global__ __launch_bounds__(256) void aggregate(
    const float* __restrict__ h, const int* __restrict__ rowptr,
    const int* __restrict__ epack, const float* __restrict__ emb,
    float* __restrict__ agg, int N)
{
    const int node = blockIdx.x * 4 + (threadIdx.x >> 6);
    const int lane = threadIdx.x & 63;
    if (node >= N) return;

    int start = (node == 0) ? 0 : rowptr[node - 1];
    int end   = rowptr[node];
    start = __builtin_amdgcn_readfirstlane(start);
    end   = __builtin_amdgcn_readfirstlane(end);

    const float2* __restrict__ h2 = (const float2*)h;
    const float2* __restrict__ e2 = (const float2*)emb;

    float ax = 0.f, ay = 0.f;
    int j = start;
    for (; j + 1 < end; j += 2) {
        const int p0 = __builtin_amdgcn_readfirstlane(epack[j]);
        const int p1 = __builtin_amdgcn_readfirstlane(epack[j + 1]);
        const int s0 = p0 & 0xFFFFF, a0 = p0 >> 20;
        const int s1 = p1 & 0xFFFFF, a1 = p1 >> 20;
        const float2 h0 = h2[s0 * 64 + lane];
        const float2 h1 = h2[s1 * 64 + lane];
        const float2 e0 = e2[a0 * 64 + lane];
        const float2 e1 = e2[a1 * 64 + lane];
        ax += fmaxf(h0.x + e0.x, 0.f) + fmaxf(h1.x + e1.x, 0.f);
        ay += fmaxf(h0.y + e0.y, 0.f) + fmaxf(h1.y + e1.y, 0.f);
    }
    if (j < end) {
        const int p0 = __builtin_amdgcn_readfirstlane(epack[j]);
        const int s0 = p0 & 0xFFFFF, a0 = p0 >> 20;
        const float2 h0 = h2[s0 * 64 + lane];
        const float2 e0 = e2[a0 * 64 + lane];
        ax += fmaxf(h0.x + e0.x, 0.f);
        ay += fmaxf(h0.y + e0.y, 0.f);
    }
    float2 o; o.x = ax; o.y = ay;
    ((float2*)agg)[node * 64 + lane] = o;
}

// ---------------- output projection ----------------
__global__ __launch_bounds__(256) void out_proj(
    const float* __restrict__ h, const float* __restrict__ Wout,
    const float* __restrict__ bout, float* __restrict__ out, int N)
{
    const int gt = blockIdx.x * 256 + threadIdx.x;
    const int r = gt >> 2;
    if (r >= N) return;
    const int q = gt & 3;

    const float* hr = &h[r * D + q * 32];
    const float* wr = &Wout[q * 32];
    float acc = 0.f;
    #pragma unroll
    for (int k = 0; k < 32; k += 4) {
        const float4 hv = ld4(hr + k);
        const float4 wv = ld4(wr + k);
        acc += hv.x * wv.x + hv.y * wv.y + hv.z * wv.z + hv.w * wv.w;
    }
    acc += __shfl_xor(acc, 1);
    acc += __shfl_xor(acc, 2);
    if (q == 0) out[r] = acc + bout[0];
}

extern "C" void kernel_launch(void* const* d_in, const int* in_sizes, int n_in,
                              void* d_out, int out_size, void* d_ws, size_t ws_size,
                              hipStream_t stream)
{
    const float* x     = (const float*)d_in[0];
    const int*   ei    = (const int*)  d_in[1];
    const int*   attr  = (const int*)  d_in[2];
    const float* emb   = (const float*)d_in[3];
    const float* Win   = (const float*)d_in[4];
    const float* b_in  = (const float*)d_in[5];
    const float* W1_0  = (const float*)d_in[6];
    const float* b1_0  = (const float*)d_in[7];
    const float* W2_0  = (const float*)d_in[8];
    const float* b2_0  = (const float*)d_in[9];
    const float* W1_1  = (const float*)d_in[10];
    const float* b1_1  = (const float*)d_in[11];
    const float* W2_1  = (const float*)d_in[12];
    const float* b2_1  = (const float*)d_in[13];
    const float* Wout  = (const float*)d_in[14];
    const float* b_out = (const float*)d_in[15];
    float* out = (float*)d_out;

    const int N = NN;
    const int E = in_sizes[2];
    const int* srcp = ei;
    const int* dstp = ei + E;

    // workspace layout
    float* h      = (float*)d_ws;                    // N*D
    float* agg    = h + (size_t)N * D;               // N*D
    int*   deg    = (int*)(agg + (size_t)N * D);     // N
    int*   rowptr = deg + N;                         // N
    int*   epack  = rowptr + N;                      // E
    int*   bsum   = epack + E;                       // <=512
    int*   boff   = bsum + 512;                      // <=512
    unsigned short* wp = (unsigned short*)(boff + 512); // 5 * 2 * 16384 shorts
    unsigned short* Whi[5], *Wlo[5];
    for (int i = 0; i < 5; ++i) {
        Whi[i] = wp + (size_t)i * 2 * D * D;
        Wlo[i] = Whi[i] + D * D;
    }

    dim3 blk(256);
    const int nb    = (N + 255) / 256;
    const int eg    = (E + 255) / 256;
    const int ggrid = (N + 127) / 128;
    const int pgrid = (D * D + 255) / 256;

    // ---- W prepack (5 weight matrices -> fragment-ordered bf16 hi/lo) ----
    prepack_w<<<pgrid, blk, 0, stream>>>(Win,  Whi[0], Wlo[0]);
    prepack_w<<<pgrid, blk, 0, stream>>>(W1_0, Whi[1], Wlo[1]);
    prepack_w<<<pgrid, blk, 0, stream>>>(W2_0, Whi[2], Wlo[2]);
    prepack_w<<<pgrid, blk, 0, stream>>>(W1_1, Whi[3], Wlo[3]);
    prepack_w<<<pgrid, blk, 0, stream>>>(W2_1, Whi[4], Wlo[4]);

    // ---- CSR build (once; reused by both layers) ----
    hipMemsetAsync(deg, 0, (size_t)N * sizeof(int), stream);
    hist_kernel<<<eg, blk, 0, stream>>>(dstp, deg, E);
    scan_bsum<<<nb, blk, 0, stream>>>(deg, bsum, N);
    scan_small<<<1, 512, 0, stream>>>(bsum, boff, nb);
    scan_final<<<nb, blk, 0, stream>>>(deg, boff, rowptr, N);
    scatter_kernel<<<eg, blk, 0, stream>>>(srcp, dstp, attr, rowptr, epack, E);

    // ---- h = x @ Win + b_in ----
    gemm_mfma<false, false, false><<<ggrid, blk, 0, stream>>>(
        x, nullptr, Whi[0], Wlo[0], b_in, nullptr, h, N);

    for (int l = 0; l < 2; ++l) {
        const unsigned short* w1h = l ? Whi[3] : Whi[1];
        const unsigned short* w1l = l ? Wlo[3] : Wlo[1];
        const unsigned short* w2h = l ? Whi[4] : Whi[2];
        const unsigned short* w2l = l ? Wlo[4] : Wlo[2];
        const float* b1 = l ? b1_1 : b1_0;
        const float* b2 = l ? b2_1 : b2_0;

        aggregate<<<(N + 3) / 4, blk, 0, stream>>>(h, rowptr, epack, emb, agg, N);
        // u = relu((agg + h) @ W1 + b1)   (in-place into agg: row-local)
        gemm_mfma<true, false, true><<<ggrid, blk, 0, stream>>>(
            agg, h, w1h, w1l, b1, nullptr, agg, N);
        // h = relu(u @ W2 + b2 + h)       (in-place into h: row-local)
        gemm_mfma<false, true, true><<<ggrid, blk, 0, stream>>>(
            agg, nullptr, w2h, w2l, b2, h, h, N);
    }

    out_proj<<<(N * 4 + 255) / 256, blk, 0, stream>>>(h, Wout, b_out, out, N);
}

// Round 4
// 712.149 us; speedup vs baseline: 8.2320x; 1.1748x over previous
//
#include <hip/hip_runtime.h>

#define NN 100000
#define D 128
#define CHUNK 4096
#define BCSTRIDE 392

typedef __attribute__((ext_vector_type(8))) short short8;
typedef __attribute__((ext_vector_type(4))) float f32x4;

__device__ __forceinline__ float4 ld4(const float* p) { return *(const float4*)p; }

__device__ __forceinline__ unsigned short f2bf(float f) {
    unsigned int u = __float_as_uint(f);
    unsigned int r = u + 0x7fffu + ((u >> 16) & 1u);   // RNE
    return (unsigned short)(r >> 16);
}
__device__ __forceinline__ float bf2f(unsigned short h) {
    return __uint_as_float(((unsigned int)h) << 16);
}

// ---------------- W prepack: fragment-ordered hi/lo bf16 ----------------
__global__ __launch_bounds__(256) void prepack_w(
    const float* __restrict__ W, unsigned short* __restrict__ hi,
    unsigned short* __restrict__ lo)
{
    const int t = blockIdx.x * 256 + threadIdx.x;
    if (t >= D * D) return;
    const int j  = t & 7;
    const int L  = (t >> 3) & 63;
    const int ks = (t >> 9) & 3;
    const int nt = t >> 11;
    const float v = W[(ks * 32 + (L >> 4) * 8 + j) * D + nt * 16 + (L & 15)];
    const unsigned short h = f2bf(v);
    hi[t] = h;
    lo[t] = f2bf(v - bf2f(h));
}

// ---------------- split-bf16 MFMA GEMM ----------------
template<bool HAS_A2, bool HAS_RES, bool RELU>
__global__ __launch_bounds__(256) void gemm_mfma(
    const float* __restrict__ A1, const float* __restrict__ A2,
    const unsigned short* __restrict__ Whi, const unsigned short* __restrict__ Wlo,
    const float* __restrict__ bias, const float* res, float* out, int N)
{
    const int t  = threadIdx.x;
    const int wv = t >> 6;
    const int L  = t & 63;
    const int lr = L & 15;
    const int q  = L >> 4;
    const int m0 = blockIdx.x * 128 + wv * 32;

    f32x4 acc[2][8];
    #pragma unroll
    for (int mi = 0; mi < 2; ++mi)
        #pragma unroll
        for (int nt = 0; nt < 8; ++nt)
            acc[mi][nt] = (f32x4){0.f, 0.f, 0.f, 0.f};

    #pragma unroll
    for (int ks = 0; ks < 4; ++ks) {
        short8 ahi[2], alo[2];
        #pragma unroll
        for (int mi = 0; mi < 2; ++mi) {
            const int row = m0 + mi * 16 + lr;
            float v[8];
            if (row < N) {
                const float* p = &A1[row * D + ks * 32 + q * 8];
                const float4 x0 = ld4(p), x1 = ld4(p + 4);
                v[0] = x0.x; v[1] = x0.y; v[2] = x0.z; v[3] = x0.w;
                v[4] = x1.x; v[5] = x1.y; v[6] = x1.z; v[7] = x1.w;
                if (HAS_A2) {
                    const float* p2 = &A2[row * D + ks * 32 + q * 8];
                    const float4 y0 = ld4(p2), y1 = ld4(p2 + 4);
                    v[0] += y0.x; v[1] += y0.y; v[2] += y0.z; v[3] += y0.w;
                    v[4] += y1.x; v[5] += y1.y; v[6] += y1.z; v[7] += y1.w;
                }
            } else {
                #pragma unroll
                for (int j = 0; j < 8; ++j) v[j] = 0.f;
            }
            #pragma unroll
            for (int j = 0; j < 8; ++j) {
                const unsigned short h = f2bf(v[j]);
                ahi[mi][j] = (short)h;
                alo[mi][j] = (short)f2bf(v[j] - bf2f(h));
            }
        }
        #pragma unroll
        for (int nt = 0; nt < 8; ++nt) {
            const int base = ((nt * 4 + ks) * 64 + L) * 8;
            const short8 bhi = *(const short8*)&Whi[base];
            const short8 blo = *(const short8*)&Wlo[base];
            #pragma unroll
            for (int mi = 0; mi < 2; ++mi) {
                acc[mi][nt] = __builtin_amdgcn_mfma_f32_16x16x32_bf16(alo[mi], bhi, acc[mi][nt], 0, 0, 0);
                acc[mi][nt] = __builtin_amdgcn_mfma_f32_16x16x32_bf16(ahi[mi], blo, acc[mi][nt], 0, 0, 0);
                acc[mi][nt] = __builtin_amdgcn_mfma_f32_16x16x32_bf16(ahi[mi], bhi, acc[mi][nt], 0, 0, 0);
            }
        }
    }

    #pragma unroll
    for (int nt = 0; nt < 8; ++nt) {
        const float b = bias[nt * 16 + lr];
        #pragma unroll
        for (int mi = 0; mi < 2; ++mi) {
            #pragma unroll
            for (int r = 0; r < 4; ++r) {
                const int grow = m0 + mi * 16 + q * 4 + r;
                if (grow < N) {
                    float o = acc[mi][nt][r] + b;
                    if (HAS_RES) o += res[grow * D + nt * 16 + lr];
                    if (RELU)    o = fmaxf(o, 0.f);
                    out[grow * D + nt * 16 + lr] = o;
                }
            }
        }
    }
}

// ---------------- binned CSR build ----------------
// A1: per-block LDS histogram of coarse bins (dst>>8); save counts, add totals
__global__ __launch_bounds__(256) void bin_count(
    const int* __restrict__ dst, int* __restrict__ blkcnt,
    int* __restrict__ binTotal, int E, int nbins)
{
    __shared__ int hist[512];
    const int t = threadIdx.x;
    const int i = blockIdx.x;
    for (int k = t; k < nbins; k += 256) hist[k] = 0;
    __syncthreads();
    const int e0 = i * CHUNK;
    const int e1 = min(E, e0 + CHUNK);
    for (int e = e0 + t; e < e1; e += 256) atomicAdd(&hist[dst[e] >> 8], 1);
    __syncthreads();
    for (int k = t; k < nbins; k += 256) {
        const int c = hist[k];
        blkcnt[i * BCSTRIDE + k] = c;
        if (c) atomicAdd(&binTotal[k], c);
    }
}

// S: exclusive scan of bin totals -> binStart[0..nbins], binCursor
__global__ __launch_bounds__(512) void bin_scan(
    const int* __restrict__ binTotal, int* __restrict__ binStart,
    int* __restrict__ binCursor, int nbins)
{
    __shared__ int s[512];
    const int t = threadIdx.x;
    const int v = (t < nbins) ? binTotal[t] : 0;
    s[t] = v;
    __syncthreads();
    for (int off = 1; off < 512; off <<= 1) {
        const int x = (t >= off) ? s[t - off] : 0;
        __syncthreads();
        s[t] += x;
        __syncthreads();
    }
    if (t < nbins) { binStart[t] = s[t] - v; binCursor[t] = s[t] - v; }
    if (t == 0)    binStart[nbins] = s[511];
}

// A2: reserve per-(block,bin) runs, write {src|attr<<20, dst} bin-grouped
__global__ __launch_bounds__(256) void bin_scatter(
    const int* __restrict__ src, const int* __restrict__ dst,
    const int* __restrict__ attr, const int* __restrict__ blkcnt,
    int* __restrict__ binCursor, int2* __restrict__ binned, int E, int nbins)
{
    __shared__ int cur[512];
    const int t = threadIdx.x;
    const int i = blockIdx.x;
    for (int k = t; k < nbins; k += 256) {
        const int c = blkcnt[i * BCSTRIDE + k];
        if (c) cur[k] = atomicAdd(&binCursor[k], c);
    }
    __syncthreads();
    const int e0 = i * CHUNK;
    const int e1 = min(E, e0 + CHUNK);
    for (int e = e0 + t; e < e1; e += 256) {
        const int d = dst[e];
        const int p = atomicAdd(&cur[d >> 8], 1);
        binned[p] = make_int2(src[e] | (attr[e] << 20), d);
    }
}

// B: per-bin: node histogram + scan -> rowptr (END offsets), scatter epack
__global__ __launch_bounds__(256) void bin_build(
    const int2* __restrict__ binned, const int* __restrict__ binStart,
    int* __restrict__ rowptr, int* __restrict__ epack, int N)
{
    __shared__ int hist[256];
    __shared__ int scn[256];
    __shared__ int curn[256];
    const int t = threadIdx.x;
    const int b = blockIdx.x;
    hist[t] = 0;
    __syncthreads();
    const int ebeg = binStart[b];
    const int eend = binStart[b + 1];
    for (int e = ebeg + t; e < eend; e += 256) atomicAdd(&hist[binned[e].y & 255], 1);
    __syncthreads();
    scn[t] = hist[t];
    __syncthreads();
    for (int off = 1; off < 256; off <<= 1) {
        const int x = (t >= off) ? scn[t - off] : 0;
        __syncthreads();
        scn[t] += x;
        __syncthreads();
    }
    const int node = b * 256 + t;
    if (node < N) rowptr[node] = ebeg + scn[t];
    curn[t] = ebeg + scn[t] - hist[t];
    __syncthreads();
    for (int e = ebeg + t; e < eend; e += 256) {
        const int2 v = binned[e];
        const int p = atomicAdd(&curn[v.y & 255], 1);
        epack[p] = v.x;
    }
}

// ---------------- CSR aggregate: one wave per node ----------------
__global__ __launch_bounds__(256) void aggregate(
    const float* __restrict__ h, const int* __restrict__ rowptr,
    const int* __restrict__ epack, const float* __restrict__ emb,
    float* __restrict__ agg, int N)
{
    const int node = blockIdx.x * 4 + (threadIdx.x >> 6);
    const int lane = threadIdx.x & 63;
    if (node >= N) return;

    int start = (node == 0) ? 0 : rowptr[node - 1];
    int end   = rowptr[node];
    start = __builtin_amdgcn_readfirstlane(start);
    end   = __builtin_amdgcn_readfirstlane(end);

    const float2* __restrict__ h2 = (const float2*)h;
    const float2* __restrict__ e2 = (const float2*)emb;

    float ax = 0.f, ay = 0.f;
    int j = start;
    for (; j + 1 < end; j += 2) {
        const int p0 = __builtin_amdgcn_readfirstlane(epack[j]);
        const int p1 = __builtin_amdgcn_readfirstlane(epack[j + 1]);
        const int s0 = p0 & 0xFFFFF, a0 = p0 >> 20;
        const int s1 = p1 & 0xFFFFF, a1 = p1 >> 20;
        const float2 h0 = h2[s0 * 64 + lane];
        const float2 h1 = h2[s1 * 64 + lane];
        const float2 e0 = e2[a0 * 64 + lane];
        const float2 e1 = e2[a1 * 64 + lane];
        ax += fmaxf(h0.x + e0.x, 0.f) + fmaxf(h1.x + e1.x, 0.f);
        ay += fmaxf(h0.y + e0.y, 0.f) + fmaxf(h1.y + e1.y, 0.f);
    }
    if (j < end) {
        const int p0 = __builtin_amdgcn_readfirstlane(epack[j]);
        const int s0 = p0 & 0xFFFFF, a0 = p0 >> 20;
        const float2 h0 = h2[s0 * 64 + lane];
        const float2 e0 = e2[a0 * 64 + lane];
        ax += fmaxf(h0.x + e0.x, 0.f);
        ay += fmaxf(h0.y + e0.y, 0.f);
    }
    float2 o; o.x = ax; o.y = ay;
    ((float2*)agg)[node * 64 + lane] = o;
}

// ---------------- output projection ----------------
__global__ __launch_bounds__(256) void out_proj(
    const float* __restrict__ h, const float* __restrict__ Wout,
    const float* __restrict__ bout, float* __restrict__ out, int N)
{
    const int gt = blockIdx.x * 256 + threadIdx.x;
    const int r = gt >> 2;
    if (r >= N) return;
    const int q = gt & 3;

    const float* hr = &h[r * D + q * 32];
    const float* wr = &Wout[q * 32];
    float acc = 0.f;
    #pragma unroll
    for (int k = 0; k < 32; k += 4) {
        const float4 hv = ld4(hr + k);
        const float4 wv = ld4(wr + k);
        acc += hv.x * wv.x + hv.y * wv.y + hv.z * wv.z + hv.w * wv.w;
    }
    acc += __shfl_xor(acc, 1);
    acc += __shfl_xor(acc, 2);
    if (q == 0) out[r] = acc + bout[0];
}

extern "C" void kernel_launch(void* const* d_in, const int* in_sizes, int n_in,
                              void* d_out, int out_size, void* d_ws, size_t ws_size,
                              hipStream_t stream)
{
    const float* x     = (const float*)d_in[0];
    const int*   ei    = (const int*)  d_in[1];
    const int*   attr  = (const int*)  d_in[2];
    const float* emb   = (const float*)d_in[3];
    const float* Win   = (const float*)d_in[4];
    const float* b_in  = (const float*)d_in[5];
    const float* W1_0  = (const float*)d_in[6];
    const float* b1_0  = (const float*)d_in[7];
    const float* W2_0  = (const float*)d_in[8];
    const float* b2_0  = (const float*)d_in[9];
    const float* W1_1  = (const float*)d_in[10];
    const float* b1_1  = (const float*)d_in[11];
    const float* W2_1  = (const float*)d_in[12];
    const float* b2_1  = (const float*)d_in[13];
    const float* Wout  = (const float*)d_in[14];
    const float* b_out = (const float*)d_in[15];
    float* out = (float*)d_out;

    const int N = NN;
    const int E = in_sizes[2];
    const int* srcp = ei;
    const int* dstp = ei + E;
    const int nbins = (N + 255) >> 8;            // 391
    const int eblocks = (E + CHUNK - 1) / CHUNK; // 391

    // persistent workspace
    float* h      = (float*)d_ws;                    // N*D
    float* agg    = h + (size_t)N * D;               // N*D
    int*   rowptr = (int*)(agg + (size_t)N * D);     // N
    int*   epack  = rowptr + N;                      // E
    unsigned short* wp = (unsigned short*)(epack + E);
    unsigned short* Whi[5], *Wlo[5];
    for (int i = 0; i < 5; ++i) {
        Whi[i] = wp + (size_t)i * 2 * D * D;
        Wlo[i] = Whi[i] + D * D;
    }
    // CSR-build scratch aliased into agg (dead until first aggregate)
    int2* binned    = (int2*)agg;                         // E
    int*  blkcnt    = (int*)(binned + E);                 // eblocks*BCSTRIDE
    int*  binTotal  = blkcnt + eblocks * BCSTRIDE;        // nbins
    int*  binStart  = binTotal + BCSTRIDE;                // nbins+1
    int*  binCursor = binStart + BCSTRIDE;                // nbins

    dim3 blk(256);
    const int ggrid = (N + 127) / 128;
    const int pgrid = (D * D + 255) / 256;

    // ---- W prepack ----
    prepack_w<<<pgrid, blk, 0, stream>>>(Win,  Whi[0], Wlo[0]);
    prepack_w<<<pgrid, blk, 0, stream>>>(W1_0, Whi[1], Wlo[1]);
    prepack_w<<<pgrid, blk, 0, stream>>>(W2_0, Whi[2], Wlo[2]);
    prepack_w<<<pgrid, blk, 0, stream>>>(W1_1, Whi[3], Wlo[3]);
    prepack_w<<<pgrid, blk, 0, stream>>>(W2_1, Whi[4], Wlo[4]);

    // ---- binned CSR build ----
    hipMemsetAsync(binTotal, 0, BCSTRIDE * sizeof(int), stream);
    bin_count<<<eblocks, blk, 0, stream>>>(dstp, blkcnt, binTotal, E, nbins);
    bin_scan<<<1, 512, 0, stream>>>(binTotal, binStart, binCursor, nbins);
    bin_scatter<<<eblocks, blk, 0, stream>>>(srcp, dstp, attr, blkcnt, binCursor, binned, E, nbins);
    bin_build<<<nbins, blk, 0, stream>>>(binned, binStart, rowptr, epack, N);

    // ---- h = x @ Win + b_in ----
    gemm_mfma<false, false, false><<<ggrid, blk, 0, stream>>>(
        x, nullptr, Whi[0], Wlo[0], b_in, nullptr, h, N);

    for (int l = 0; l < 2; ++l) {
        const unsigned short* w1h = l ? Whi[3] : Whi[1];
        const unsigned short* w1l = l ? Wlo[3] : Wlo[1];
        const unsigned short* w2h = l ? Whi[4] : Whi[2];
        const unsigned short* w2l = l ? Wlo[4] : Wlo[2];
        const float* b1 = l ? b1_1 : b1_0;
        const float* b2 = l ? b2_1 : b2_0;

        aggregate<<<(N + 3) / 4, blk, 0, stream>>>(h, rowptr, epack, emb, agg, N);
        gemm_mfma<true, false, true><<<ggrid, blk, 0, stream>>>(
            agg, h, w1h, w1l, b1, nullptr, agg, N);
        gemm_mfma<false, true, true><<<ggrid, blk, 0, stream>>>(
            agg, nullptr, w2h, w2l, b2, h, h, N);
    }

    out_proj<<<(N * 4 + 255) / 256, blk, 0, stream>>>(h, Wout, b_out, out, N);
}

// Round 5
// 657.653 us; speedup vs baseline: 8.9142x; 1.0829x over previous
//
#include <hip/hip_runtime.h>

#define NN 100000
#define D 128
#define CHUNK 4096
#define BCSTRIDE 392

typedef __attribute__((ext_vector_type(8))) short short8;
typedef __attribute__((ext_vector_type(8))) unsigned short ushort8;
typedef __attribute__((ext_vector_type(4))) float f32x4;

__device__ __forceinline__ float4 ld4(const float* p) { return *(const float4*)p; }

__device__ __forceinline__ unsigned short f2bf(float f) {
    unsigned int u = __float_as_uint(f);
    unsigned int r = u + 0x7fffu + ((u >> 16) & 1u);   // RNE
    return (unsigned short)(r >> 16);
}
__device__ __forceinline__ float bf2f(unsigned short h) {
    return __uint_as_float(((unsigned int)h) << 16);
}

// ---------------- W prepack: fragment-ordered hi/lo bf16 ----------------
__global__ __launch_bounds__(256) void prepack_w(
    const float* __restrict__ W, unsigned short* __restrict__ hi,
    unsigned short* __restrict__ lo)
{
    const int t = blockIdx.x * 256 + threadIdx.x;
    if (t >= D * D) return;
    const int j  = t & 7;
    const int L  = (t >> 3) & 63;
    const int ks = (t >> 9) & 3;
    const int nt = t >> 11;
    const float v = W[(ks * 32 + (L >> 4) * 8 + j) * D + nt * 16 + (L & 15)];
    const unsigned short h = f2bf(v);
    hi[t] = h;
    lo[t] = f2bf(v - bf2f(h));
}

// ---------------- split-bf16 MFMA GEMM ----------------
// A = A1 (fp32) [+ A2 (hi/lo bf16)]; res = hi/lo bf16; out = fp32 or hi/lo.
template<bool HAS_A2, bool HAS_RES, bool OUT_SPLIT, bool RELU>
__global__ __launch_bounds__(256) void gemm_mfma(
    const float* __restrict__ A1,
    const unsigned short* __restrict__ A2hi, const unsigned short* __restrict__ A2lo,
    const unsigned short* __restrict__ Whi, const unsigned short* __restrict__ Wlo,
    const float* __restrict__ bias,
    const unsigned short* res_hi, const unsigned short* res_lo,
    float* out_f, unsigned short* out_hi, unsigned short* out_lo, int N)
{
    const int t  = threadIdx.x;
    const int wv = t >> 6;
    const int L  = t & 63;
    const int lr = L & 15;
    const int q  = L >> 4;
    const int m0 = blockIdx.x * 128 + wv * 32;

    f32x4 acc[2][8];
    #pragma unroll
    for (int mi = 0; mi < 2; ++mi)
        #pragma unroll
        for (int nt = 0; nt < 8; ++nt)
            acc[mi][nt] = (f32x4){0.f, 0.f, 0.f, 0.f};

    #pragma unroll
    for (int ks = 0; ks < 4; ++ks) {
        short8 ahi[2], alo[2];
        #pragma unroll
        for (int mi = 0; mi < 2; ++mi) {
            const int row = m0 + mi * 16 + lr;
            float v[8];
            if (row < N) {
                const int off = row * D + ks * 32 + q * 8;
                const float4 x0 = ld4(&A1[off]), x1 = ld4(&A1[off + 4]);
                v[0] = x0.x; v[1] = x0.y; v[2] = x0.z; v[3] = x0.w;
                v[4] = x1.x; v[5] = x1.y; v[6] = x1.z; v[7] = x1.w;
                if (HAS_A2) {
                    const ushort8 hh = *(const ushort8*)&A2hi[off];
                    const ushort8 ll = *(const ushort8*)&A2lo[off];
                    #pragma unroll
                    for (int j = 0; j < 8; ++j)
                        v[j] += bf2f(hh[j]) + bf2f(ll[j]);
                }
            } else {
                #pragma unroll
                for (int j = 0; j < 8; ++j) v[j] = 0.f;
            }
            #pragma unroll
            for (int j = 0; j < 8; ++j) {
                const unsigned short h = f2bf(v[j]);
                ahi[mi][j] = (short)h;
                alo[mi][j] = (short)f2bf(v[j] - bf2f(h));
            }
        }
        #pragma unroll
        for (int nt = 0; nt < 8; ++nt) {
            const int base = ((nt * 4 + ks) * 64 + L) * 8;
            const short8 bhi = *(const short8*)&Whi[base];
            const short8 blo = *(const short8*)&Wlo[base];
            #pragma unroll
            for (int mi = 0; mi < 2; ++mi) {
                acc[mi][nt] = __builtin_amdgcn_mfma_f32_16x16x32_bf16(alo[mi], bhi, acc[mi][nt], 0, 0, 0);
                acc[mi][nt] = __builtin_amdgcn_mfma_f32_16x16x32_bf16(ahi[mi], blo, acc[mi][nt], 0, 0, 0);
                acc[mi][nt] = __builtin_amdgcn_mfma_f32_16x16x32_bf16(ahi[mi], bhi, acc[mi][nt], 0, 0, 0);
            }
        }
    }

    #pragma unroll
    for (int nt = 0; nt < 8; ++nt) {
        const float b = bias[nt * 16 + lr];
        #pragma unroll
        for (int mi = 0; mi < 2; ++mi) {
            #pragma unroll
            for (int r = 0; r < 4; ++r) {
                const int grow = m0 + mi * 16 + q * 4 + r;
                if (grow < N) {
                    const int idx = grow * D + nt * 16 + lr;
                    float o = acc[mi][nt][r] + b;
                    if (HAS_RES) o += bf2f(res_hi[idx]) + bf2f(res_lo[idx]);
                    if (RELU)    o = fmaxf(o, 0.f);
                    if (OUT_SPLIT) {
                        const unsigned short hi = f2bf(o);
                        out_hi[idx] = hi;
                        out_lo[idx] = f2bf(o - bf2f(hi));
                    } else {
                        out_f[idx] = o;
                    }
                }
            }
        }
    }
}

// ---------------- binned CSR build ----------------
__global__ __launch_bounds__(256) void bin_count(
    const int* __restrict__ dst, int* __restrict__ blkcnt,
    int* __restrict__ binTotal, int E, int nbins)
{
    __shared__ int hist[512];
    const int t = threadIdx.x;
    const int i = blockIdx.x;
    for (int k = t; k < nbins; k += 256) hist[k] = 0;
    __syncthreads();
    const int e0 = i * CHUNK;
    const int e1 = min(E, e0 + CHUNK);
    for (int e = e0 + t; e < e1; e += 256) atomicAdd(&hist[dst[e] >> 8], 1);
    __syncthreads();
    for (int k = t; k < nbins; k += 256) {
        const int c = hist[k];
        blkcnt[i * BCSTRIDE + k] = c;
        if (c) atomicAdd(&binTotal[k], c);
    }
}

__global__ __launch_bounds__(512) void bin_scan(
    const int* __restrict__ binTotal, int* __restrict__ binStart,
    int* __restrict__ binCursor, int nbins)
{
    __shared__ int s[512];
    const int t = threadIdx.x;
    const int v = (t < nbins) ? binTotal[t] : 0;
    s[t] = v;
    __syncthreads();
    for (int off = 1; off < 512; off <<= 1) {
        const int x = (t >= off) ? s[t - off] : 0;
        __syncthreads();
        s[t] += x;
        __syncthreads();
    }
    if (t < nbins) { binStart[t] = s[t] - v; binCursor[t] = s[t] - v; }
    if (t == 0)    binStart[nbins] = s[511];
}

__global__ __launch_bounds__(256) void bin_scatter(
    const int* __restrict__ src, const int* __restrict__ dst,
    const int* __restrict__ attr, const int* __restrict__ blkcnt,
    int* __restrict__ binCursor, int2* __restrict__ binned, int E, int nbins)
{
    __shared__ int cur[512];
    const int t = threadIdx.x;
    const int i = blockIdx.x;
    for (int k = t; k < nbins; k += 256) {
        const int c = blkcnt[i * BCSTRIDE + k];
        if (c) cur[k] = atomicAdd(&binCursor[k], c);
    }
    __syncthreads();
    const int e0 = i * CHUNK;
    const int e1 = min(E, e0 + CHUNK);
    for (int e = e0 + t; e < e1; e += 256) {
        const int d = dst[e];
        const int p = atomicAdd(&cur[d >> 8], 1);
        binned[p] = make_int2(src[e] | (attr[e] << 20), d);
    }
}

__global__ __launch_bounds__(256) void bin_build(
    const int2* __restrict__ binned, const int* __restrict__ binStart,
    int* __restrict__ rowptr, int* __restrict__ epack, int N)
{
    __shared__ int hist[256];
    __shared__ int scn[256];
    __shared__ int curn[256];
    const int t = threadIdx.x;
    const int b = blockIdx.x;
    hist[t] = 0;
    __syncthreads();
    const int ebeg = binStart[b];
    const int eend = binStart[b + 1];
    for (int e = ebeg + t; e < eend; e += 256) atomicAdd(&hist[binned[e].y & 255], 1);
    __syncthreads();
    scn[t] = hist[t];
    __syncthreads();
    for (int off = 1; off < 256; off <<= 1) {
        const int x = (t >= off) ? scn[t - off] : 0;
        __syncthreads();
        scn[t] += x;
        __syncthreads();
    }
    const int node = b * 256 + t;
    if (node < N) rowptr[node] = ebeg + scn[t];
    curn[t] = ebeg + scn[t] - hist[t];
    __syncthreads();
    for (int e = ebeg + t; e < eend; e += 256) {
        const int2 v = binned[e];
        const int p = atomicAdd(&curn[v.y & 255], 1);
        epack[p] = v.x;
    }
}

// ---------------- CSR aggregate: one wave per node, bf16-hi gather ----------------
__global__ __launch_bounds__(256) void aggregate(
    const unsigned int* __restrict__ hu,      // h_hi viewed as uint (2 bf16/lane)
    const int* __restrict__ rowptr, const int* __restrict__ epack,
    const float* __restrict__ emb, float* __restrict__ agg, int N)
{
    const int node = blockIdx.x * 4 + (threadIdx.x >> 6);
    const int lane = threadIdx.x & 63;
    if (node >= N) return;

    int start = (node == 0) ? 0 : rowptr[node - 1];
    int end   = rowptr[node];
    start = __builtin_amdgcn_readfirstlane(start);
    end   = __builtin_amdgcn_readfirstlane(end);

    const float2* __restrict__ e2 = (const float2*)emb;

    float ax = 0.f, ay = 0.f;
    int j = start;
    for (; j + 3 < end; j += 4) {
        const int p0 = __builtin_amdgcn_readfirstlane(epack[j]);
        const int p1 = __builtin_amdgcn_readfirstlane(epack[j + 1]);
        const int p2 = __builtin_amdgcn_readfirstlane(epack[j + 2]);
        const int p3 = __builtin_amdgcn_readfirstlane(epack[j + 3]);
        const unsigned int u0 = hu[(p0 & 0xFFFFF) * 64 + lane];
        const unsigned int u1 = hu[(p1 & 0xFFFFF) * 64 + lane];
        const unsigned int u2 = hu[(p2 & 0xFFFFF) * 64 + lane];
        const unsigned int u3 = hu[(p3 & 0xFFFFF) * 64 + lane];
        const float2 e0 = e2[(p0 >> 20) * 64 + lane];
        const float2 e1 = e2[(p1 >> 20) * 64 + lane];
        const float2 ee2 = e2[(p2 >> 20) * 64 + lane];
        const float2 e3 = e2[(p3 >> 20) * 64 + lane];
        ax += fmaxf(__uint_as_float(u0 << 16) + e0.x, 0.f)
            + fmaxf(__uint_as_float(u1 << 16) + e1.x, 0.f)
            + fmaxf(__uint_as_float(u2 << 16) + ee2.x, 0.f)
            + fmaxf(__uint_as_float(u3 << 16) + e3.x, 0.f);
        ay += fmaxf(__uint_as_float(u0 & 0xffff0000u) + e0.y, 0.f)
            + fmaxf(__uint_as_float(u1 & 0xffff0000u) + e1.y, 0.f)
            + fmaxf(__uint_as_float(u2 & 0xffff0000u) + ee2.y, 0.f)
            + fmaxf(__uint_as_float(u3 & 0xffff0000u) + e3.y, 0.f);
    }
    for (; j < end; ++j) {
        const int p0 = __builtin_amdgcn_readfirstlane(epack[j]);
        const unsigned int u0 = hu[(p0 & 0xFFFFF) * 64 + lane];
        const float2 e0 = e2[(p0 >> 20) * 64 + lane];
        ax += fmaxf(__uint_as_float(u0 << 16) + e0.x, 0.f);
        ay += fmaxf(__uint_as_float(u0 & 0xffff0000u) + e0.y, 0.f);
    }
    float2 o; o.x = ax; o.y = ay;
    ((float2*)agg)[node * 64 + lane] = o;
}

// ---------------- output projection ----------------
__global__ __launch_bounds__(256) void out_proj(
    const float* __restrict__ h, const float* __restrict__ Wout,
    const float* __restrict__ bout, float* __restrict__ out, int N)
{
    const int gt = blockIdx.x * 256 + threadIdx.x;
    const int r = gt >> 2;
    if (r >= N) return;
    const int q = gt & 3;

    const float* hr = &h[r * D + q * 32];
    const float* wr = &Wout[q * 32];
    float acc = 0.f;
    #pragma unroll
    for (int k = 0; k < 32; k += 4) {
        const float4 hv = ld4(hr + k);
        const float4 wv = ld4(wr + k);
        acc += hv.x * wv.x + hv.y * wv.y + hv.z * wv.z + hv.w * wv.w;
    }
    acc += __shfl_xor(acc, 1);
    acc += __shfl_xor(acc, 2);
    if (q == 0) out[r] = acc + bout[0];
}

extern "C" void kernel_launch(void* const* d_in, const int* in_sizes, int n_in,
                              void* d_out, int out_size, void* d_ws, size_t ws_size,
                              hipStream_t stream)
{
    const float* x     = (const float*)d_in[0];
    const int*   ei    = (const int*)  d_in[1];
    const int*   attr  = (const int*)  d_in[2];
    const float* emb   = (const float*)d_in[3];
    const float* Win   = (const float*)d_in[4];
    const float* b_in  = (const float*)d_in[5];
    const float* W1_0  = (const float*)d_in[6];
    const float* b1_0  = (const float*)d_in[7];
    const float* W2_0  = (const float*)d_in[8];
    const float* b2_0  = (const float*)d_in[9];
    const float* W1_1  = (const float*)d_in[10];
    const float* b1_1  = (const float*)d_in[11];
    const float* W2_1  = (const float*)d_in[12];
    const float* b2_1  = (const float*)d_in[13];
    const float* Wout  = (const float*)d_in[14];
    const float* b_out = (const float*)d_in[15];
    float* out = (float*)d_out;

    const int N = NN;
    const int E = in_sizes[2];
    const int* srcp = ei;
    const int* dstp = ei + E;
    const int nbins = (N + 255) >> 8;
    const int eblocks = (E + CHUNK - 1) / CHUNK;

    // persistent workspace (same footprint as fp32-h layout)
    unsigned short* h_hi = (unsigned short*)d_ws;        // N*D ushort
    unsigned short* h_lo = h_hi + (size_t)N * D;         // N*D ushort
    float* agg    = (float*)(h_lo + (size_t)N * D);      // N*D float
    int*   rowptr = (int*)(agg + (size_t)N * D);         // N
    int*   epack  = rowptr + N;                          // E
    unsigned short* wp = (unsigned short*)(epack + E);   // 5*2*D*D
    unsigned short* Whi[5], *Wlo[5];
    for (int i = 0; i < 5; ++i) {
        Whi[i] = wp + (size_t)i * 2 * D * D;
        Wlo[i] = Whi[i] + D * D;
    }
    // CSR-build scratch aliased into agg (dead until first aggregate)
    int2* binned    = (int2*)agg;                         // E
    int*  blkcnt    = (int*)(binned + E);                 // eblocks*BCSTRIDE
    int*  binTotal  = blkcnt + eblocks * BCSTRIDE;        // nbins
    int*  binStart  = binTotal + BCSTRIDE;                // nbins+1
    int*  binCursor = binStart + BCSTRIDE;                // nbins

    dim3 blk(256);
    const int ggrid = (N + 127) / 128;
    const int pgrid = (D * D + 255) / 256;

    // ---- W prepack ----
    prepack_w<<<pgrid, blk, 0, stream>>>(Win,  Whi[0], Wlo[0]);
    prepack_w<<<pgrid, blk, 0, stream>>>(W1_0, Whi[1], Wlo[1]);
    prepack_w<<<pgrid, blk, 0, stream>>>(W2_0, Whi[2], Wlo[2]);
    prepack_w<<<pgrid, blk, 0, stream>>>(W1_1, Whi[3], Wlo[3]);
    prepack_w<<<pgrid, blk, 0, stream>>>(W2_1, Whi[4], Wlo[4]);

    // ---- binned CSR build ----
    hipMemsetAsync(binTotal, 0, BCSTRIDE * sizeof(int), stream);
    bin_count<<<eblocks, blk, 0, stream>>>(dstp, blkcnt, binTotal, E, nbins);
    bin_scan<<<1, 512, 0, stream>>>(binTotal, binStart, binCursor, nbins);
    bin_scatter<<<eblocks, blk, 0, stream>>>(srcp, dstp, attr, blkcnt, binCursor, binned, E, nbins);
    bin_build<<<nbins, blk, 0, stream>>>(binned, binStart, rowptr, epack, N);

    // ---- h = x @ Win + b_in  (write split h) ----
    gemm_mfma<false, false, true, false><<<ggrid, blk, 0, stream>>>(
        x, nullptr, nullptr, Whi[0], Wlo[0], b_in,
        nullptr, nullptr, nullptr, h_hi, h_lo, N);

    for (int l = 0; l < 2; ++l) {
        const unsigned short* w1h = l ? Whi[3] : Whi[1];
        const unsigned short* w1l = l ? Wlo[3] : Wlo[1];
        const unsigned short* w2h = l ? Whi[4] : Whi[2];
        const unsigned short* w2l = l ? Wlo[4] : Wlo[2];
        const float* b1 = l ? b1_1 : b1_0;
        const float* b2 = l ? b2_1 : b2_0;
        const bool last = (l == 1);

        aggregate<<<(N + 3) / 4, blk, 0, stream>>>(
            (const unsigned int*)h_hi, rowptr, epack, emb, agg, N);

        // u = relu((agg + h) @ W1 + b1)   -> agg (fp32, in-place row-local)
        gemm_mfma<true, false, false, true><<<ggrid, blk, 0, stream>>>(
            agg, h_hi, h_lo, w1h, w1l, b1,
            nullptr, nullptr, agg, nullptr, nullptr, N);

        if (!last) {
            // h = relu(u @ W2 + b2 + h)  -> split h (in-place row-local)
            gemm_mfma<false, true, true, true><<<ggrid, blk, 0, stream>>>(
                agg, nullptr, nullptr, w2h, w2l, b2,
                h_hi, h_lo, nullptr, h_hi, h_lo, N);
        } else {
            // final h -> fp32 into agg (feeds out_proj)
            gemm_mfma<false, true, false, true><<<ggrid, blk, 0, stream>>>(
                agg, nullptr, nullptr, w2h, w2l, b2,
                h_hi, h_lo, agg, nullptr, nullptr, N);
        }
    }

    out_proj<<<(N * 4 + 255) / 256, blk, 0, stream>>>(agg, Wout, b_out, out, N);
}

// Round 8
// 641.118 us; speedup vs baseline: 9.1441x; 1.0258x over previous
//
#include <hip/hip_runtime.h>

#define NN 100000
#define D 128
#define CHUNK 4096
#define BCSTRIDE 392

typedef __attribute__((ext_vector_type(8))) short short8;
typedef __attribute__((ext_vector_type(8))) unsigned short ushort8;
typedef __attribute__((ext_vector_type(4))) float f32x4;

__device__ __forceinline__ float4 ld4(const float* p) { return *(const float4*)p; }

__device__ __forceinline__ unsigned short f2bf(float f) {
    unsigned int u = __float_as_uint(f);
    unsigned int r = u + 0x7fffu + ((u >> 16) & 1u);   // RNE
    return (unsigned short)(r >> 16);
}
__device__ __forceinline__ float bf2f(unsigned short h) {
    return __uint_as_float(((unsigned int)h) << 16);
}

// ---------------- W prepack: fragment-ordered hi/lo bf16 ----------------
__global__ __launch_bounds__(256) void prepack_w(
    const float* __restrict__ W, unsigned short* __restrict__ hi,
    unsigned short* __restrict__ lo)
{
    const int t = blockIdx.x * 256 + threadIdx.x;
    if (t >= D * D) return;
    const int j  = t & 7;
    const int L  = (t >> 3) & 63;
    const int ks = (t >> 9) & 3;
    const int nt = t >> 11;
    const float v = W[(ks * 32 + (L >> 4) * 8 + j) * D + nt * 16 + (L & 15)];
    const unsigned short h = f2bf(v);
    hi[t] = h;
    lo[t] = f2bf(v - bf2f(h));
}

// ---------------- input GEMM: h(split) = x @ Win + b_in ----------------
// 256 thr / 4 waves / 128 rows; A-loads hoisted before the MFMA loop.
__global__ __launch_bounds__(256) void gemm_in(
    const float* __restrict__ A1,
    const unsigned short* __restrict__ Whi, const unsigned short* __restrict__ Wlo,
    const float* __restrict__ bias,
    unsigned short* __restrict__ out_hi, unsigned short* __restrict__ out_lo, int N)
{
    const int t  = threadIdx.x;
    const int wv = t >> 6;
    const int L  = t & 63;
    const int lr = L & 15;
    const int q  = L >> 4;
    const int m0 = blockIdx.x * 128 + wv * 32;

    // hoist ALL A loads (16 dwordx4 in flight)
    float4 a4[2][4][2];
    #pragma unroll
    for (int mi = 0; mi < 2; ++mi) {
        const int row = m0 + mi * 16 + lr;
        #pragma unroll
        for (int ks = 0; ks < 4; ++ks) {
            if (row < N) {
                const int off = row * D + ks * 32 + q * 8;
                a4[mi][ks][0] = ld4(&A1[off]);
                a4[mi][ks][1] = ld4(&A1[off + 4]);
            } else {
                a4[mi][ks][0] = make_float4(0.f, 0.f, 0.f, 0.f);
                a4[mi][ks][1] = make_float4(0.f, 0.f, 0.f, 0.f);
            }
        }
    }
    short8 ahi[2][4], alo[2][4];
    #pragma unroll
    for (int mi = 0; mi < 2; ++mi)
        #pragma unroll
        for (int ks = 0; ks < 4; ++ks) {
            const float v[8] = { a4[mi][ks][0].x, a4[mi][ks][0].y, a4[mi][ks][0].z, a4[mi][ks][0].w,
                                 a4[mi][ks][1].x, a4[mi][ks][1].y, a4[mi][ks][1].z, a4[mi][ks][1].w };
            #pragma unroll
            for (int j = 0; j < 8; ++j) {
                const unsigned short h = f2bf(v[j]);
                ahi[mi][ks][j] = (short)h;
                alo[mi][ks][j] = (short)f2bf(v[j] - bf2f(h));
            }
        }

    f32x4 acc[2][8];
    #pragma unroll
    for (int mi = 0; mi < 2; ++mi)
        #pragma unroll
        for (int nt = 0; nt < 8; ++nt)
            acc[mi][nt] = (f32x4){0.f, 0.f, 0.f, 0.f};

    #pragma unroll
    for (int ks = 0; ks < 4; ++ks)
        #pragma unroll
        for (int nt = 0; nt < 8; ++nt) {
            const int base = ((nt * 4 + ks) * 64 + L) * 8;
            const short8 bhi = *(const short8*)&Whi[base];
            const short8 blo = *(const short8*)&Wlo[base];
            #pragma unroll
            for (int mi = 0; mi < 2; ++mi) {
                acc[mi][nt] = __builtin_amdgcn_mfma_f32_16x16x32_bf16(alo[mi][ks], bhi, acc[mi][nt], 0, 0, 0);
                acc[mi][nt] = __builtin_amdgcn_mfma_f32_16x16x32_bf16(ahi[mi][ks], blo, acc[mi][nt], 0, 0, 0);
                acc[mi][nt] = __builtin_amdgcn_mfma_f32_16x16x32_bf16(ahi[mi][ks], bhi, acc[mi][nt], 0, 0, 0);
            }
        }

    #pragma unroll
    for (int nt = 0; nt < 8; ++nt) {
        const float b = bias[nt * 16 + lr];
        #pragma unroll
        for (int mi = 0; mi < 2; ++mi)
            #pragma unroll
            for (int r = 0; r < 4; ++r) {
                const int grow = m0 + mi * 16 + q * 4 + r;
                if (grow < N) {
                    const int idx = grow * D + nt * 16 + lr;
                    const float o = acc[mi][nt][r] + b;
                    const unsigned short hi = f2bf(o);
                    out_hi[idx] = hi;
                    out_lo[idx] = f2bf(o - bf2f(hi));
                }
            }
    }
}

// ---------------- fused GINE MLP: u=relu((agg+h)W1+b1); h'=relu(uW2+b2+h) ----------------
// 128 thr / 2 waves / 64 rows; u tile lives in LDS (packed bf16 hi|lo, stride 132).
template<bool LAST>
__global__ __launch_bounds__(128) void mlp_fused(
    const float* __restrict__ agg,
    const unsigned short* __restrict__ h_hi, const unsigned short* __restrict__ h_lo,
    const unsigned short* __restrict__ W1hi, const unsigned short* __restrict__ W1lo,
    const float* __restrict__ b1,
    const unsigned short* __restrict__ W2hi, const unsigned short* __restrict__ W2lo,
    const float* __restrict__ b2,
    unsigned short* __restrict__ out_hi, unsigned short* __restrict__ out_lo,
    float* __restrict__ out_f, int N)
{
    __shared__ unsigned int uT[64 * 132];   // [row][col], 2-way bank alias (free)
    const int t  = threadIdx.x;
    const int wv = t >> 6;
    const int L  = t & 63;
    const int lr = L & 15;
    const int q  = L >> 4;
    const int m0 = blockIdx.x * 64 + wv * 32;

    // ---- stage 1: A = agg + h (split), hoisted loads ----
    float4  a4[2][4][2];
    ushort8 hh[2][4], ll[2][4];
    #pragma unroll
    for (int mi = 0; mi < 2; ++mi) {
        const int row = m0 + mi * 16 + lr;
        #pragma unroll
        for (int ks = 0; ks < 4; ++ks) {
            if (row < N) {
                const int off = row * D + ks * 32 + q * 8;
                a4[mi][ks][0] = ld4(&agg[off]);
                a4[mi][ks][1] = ld4(&agg[off + 4]);
                hh[mi][ks] = *(const ushort8*)&h_hi[off];
                ll[mi][ks] = *(const ushort8*)&h_lo[off];
            } else {
                a4[mi][ks][0] = make_float4(0.f, 0.f, 0.f, 0.f);
                a4[mi][ks][1] = make_float4(0.f, 0.f, 0.f, 0.f);
                hh[mi][ks] = (ushort8)0;
                ll[mi][ks] = (ushort8)0;
            }
        }
    }
    short8 ahi[2][4], alo[2][4];
    #pragma unroll
    for (int mi = 0; mi < 2; ++mi)
        #pragma unroll
        for (int ks = 0; ks < 4; ++ks) {
            float v[8] = { a4[mi][ks][0].x, a4[mi][ks][0].y, a4[mi][ks][0].z, a4[mi][ks][0].w,
                           a4[mi][ks][1].x, a4[mi][ks][1].y, a4[mi][ks][1].z, a4[mi][ks][1].w };
            #pragma unroll
            for (int j = 0; j < 8; ++j) {
                v[j] += bf2f(hh[mi][ks][j]) + bf2f(ll[mi][ks][j]);
                const unsigned short h = f2bf(v[j]);
                ahi[mi][ks][j] = (short)h;
                alo[mi][ks][j] = (short)f2bf(v[j] - bf2f(h));
            }
        }

    f32x4 acc[2][8];
    #pragma unroll
    for (int mi = 0; mi < 2; ++mi)
        #pragma unroll
        for (int nt = 0; nt < 8; ++nt)
            acc[mi][nt] = (f32x4){0.f, 0.f, 0.f, 0.f};

    #pragma unroll
    for (int ks = 0; ks < 4; ++ks)
        #pragma unroll
        for (int nt = 0; nt < 8; ++nt) {
            const int base = ((nt * 4 + ks) * 64 + L) * 8;
            const short8 bhi = *(const short8*)&W1hi[base];
            const short8 blo = *(const short8*)&W1lo[base];
            #pragma unroll
            for (int mi = 0; mi < 2; ++mi) {
                acc[mi][nt] = __builtin_amdgcn_mfma_f32_16x16x32_bf16(alo[mi][ks], bhi, acc[mi][nt], 0, 0, 0);
                acc[mi][nt] = __builtin_amdgcn_mfma_f32_16x16x32_bf16(ahi[mi][ks], blo, acc[mi][nt], 0, 0, 0);
                acc[mi][nt] = __builtin_amdgcn_mfma_f32_16x16x32_bf16(ahi[mi][ks], bhi, acc[mi][nt], 0, 0, 0);
            }
        }

    // u = relu(acc + b1) -> LDS (packed hi|lo)
    #pragma unroll
    for (int nt = 0; nt < 8; ++nt) {
        const float b = b1[nt * 16 + lr];
        #pragma unroll
        for (int mi = 0; mi < 2; ++mi)
            #pragma unroll
            for (int r = 0; r < 4; ++r) {
                const int rloc = wv * 32 + mi * 16 + q * 4 + r;
                const float o = fmaxf(acc[mi][nt][r] + b, 0.f);
                const unsigned int hi = f2bf(o);
                const unsigned int lo = f2bf(o - bf2f((unsigned short)hi));
                uT[rloc * 132 + nt * 16 + lr] = (hi << 16) | lo;
            }
    }
    __syncthreads();

    // ---- stage 2: A = u (from LDS) ----
    short8 uhi[2][4], ulo[2][4];
    #pragma unroll
    for (int mi = 0; mi < 2; ++mi) {
        const int rloc = wv * 32 + mi * 16 + lr;
        #pragma unroll
        for (int ks = 0; ks < 4; ++ks) {
            const unsigned int* p = &uT[rloc * 132 + ks * 32 + q * 8];
            #pragma unroll
            for (int j = 0; j < 8; ++j) {
                const unsigned int v = p[j];
                uhi[mi][ks][j] = (short)(v >> 16);
                ulo[mi][ks][j] = (short)(v & 0xffffu);
            }
        }
    }

    f32x4 acc2[2][8];
    #pragma unroll
    for (int mi = 0; mi < 2; ++mi)
        #pragma unroll
        for (int nt = 0; nt < 8; ++nt)
            acc2[mi][nt] = (f32x4){0.f, 0.f, 0.f, 0.f};

    #pragma unroll
    for (int ks = 0; ks < 4; ++ks)
        #pragma unroll
        for (int nt = 0; nt < 8; ++nt) {
            const int base = ((nt * 4 + ks) * 64 + L) * 8;
            const short8 bhi = *(const short8*)&W2hi[base];
            const short8 blo = *(const short8*)&W2lo[base];
            #pragma unroll
            for (int mi = 0; mi < 2; ++mi) {
                acc2[mi][nt] = __builtin_amdgcn_mfma_f32_16x16x32_bf16(ulo[mi][ks], bhi, acc2[mi][nt], 0, 0, 0);
                acc2[mi][nt] = __builtin_amdgcn_mfma_f32_16x16x32_bf16(uhi[mi][ks], blo, acc2[mi][nt], 0, 0, 0);
                acc2[mi][nt] = __builtin_amdgcn_mfma_f32_16x16x32_bf16(uhi[mi][ks], bhi, acc2[mi][nt], 0, 0, 0);
            }
        }

    // h' = relu(acc2 + b2 + h)
    #pragma unroll
    for (int nt = 0; nt < 8; ++nt) {
        const float b = b2[nt * 16 + lr];
        #pragma unroll
        for (int mi = 0; mi < 2; ++mi)
            #pragma unroll
            for (int r = 0; r < 4; ++r) {
                const int grow = m0 + mi * 16 + q * 4 + r;
                if (grow < N) {
                    const int idx = grow * D + nt * 16 + lr;
                    float o = acc2[mi][nt][r] + b + bf2f(h_hi[idx]) + bf2f(h_lo[idx]);
                    o = fmaxf(o, 0.f);
                    if (LAST) {
                        out_f[idx] = o;
                    } else {
                        const unsigned short hi = f2bf(o);
                        out_hi[idx] = hi;
                        out_lo[idx] = f2bf(o - bf2f(hi));
                    }
                }
            }
    }
}

// ---------------- binned CSR build ----------------
__global__ __launch_bounds__(256) void bin_count(
    const int* __restrict__ dst, int* __restrict__ blkcnt,
    int* __restrict__ binTotal, int E, int nbins)
{
    __shared__ int hist[512];
    const int t = threadIdx.x;
    const int i = blockIdx.x;
    for (int k = t; k < nbins; k += 256) hist[k] = 0;
    __syncthreads();
    const int e0 = i * CHUNK;
    const int e1 = min(E, e0 + CHUNK);
    for (int e = e0 + t; e < e1; e += 256) atomicAdd(&hist[dst[e] >> 8], 1);
    __syncthreads();
    for (int k = t; k < nbins; k += 256) {
        const int c = hist[k];
        blkcnt[i * BCSTRIDE + k] = c;
        if (c) atomicAdd(&binTotal[k], c);
    }
}

__global__ __launch_bounds__(512) void bin_scan(
    const int* __restrict__ binTotal, int* __restrict__ binStart,
    int* __restrict__ binCursor, int nbins)
{
    __shared__ int s[512];
    const int t = threadIdx.x;
    const int v = (t < nbins) ? binTotal[t] : 0;
    s[t] = v;
    __syncthreads();
    for (int off = 1; off < 512; off <<= 1) {
        const int x = (t >= off) ? s[t - off] : 0;
        __syncthreads();
        s[t] += x;
        __syncthreads();
    }
    if (t < nbins) { binStart[t] = s[t] - v; binCursor[t] = s[t] - v; }
    if (t == 0)    binStart[nbins] = s[511];
}

__global__ __launch_bounds__(256) void bin_scatter(
    const int* __restrict__ src, const int* __restrict__ dst,
    const int* __restrict__ attr, const int* __restrict__ blkcnt,
    int* __restrict__ binCursor, int2* __restrict__ binned, int E, int nbins)
{
    __shared__ int cur[512];
    const int t = threadIdx.x;
    const int i = blockIdx.x;
    for (int k = t; k < nbins; k += 256) {
        const int c = blkcnt[i * BCSTRIDE + k];
        if (c) cur[k] = atomicAdd(&binCursor[k], c);
    }
    __syncthreads();
    const int e0 = i * CHUNK;
    const int e1 = min(E, e0 + CHUNK);
    for (int e = e0 + t; e < e1; e += 256) {
        const int d = dst[e];
        const int p = atomicAdd(&cur[d >> 8], 1);
        binned[p] = make_int2(src[e] | (attr[e] << 20), d);
    }
}

__global__ __launch_bounds__(256) void bin_build(
    const int2* __restrict__ binned, const int* __restrict__ binStart,
    int* __restrict__ rowptr, int* __restrict__ epack, int N)
{
    __shared__ int hist[256];
    __shared__ int scn[256];
    __shared__ int curn[256];
    const int t = threadIdx.x;
    const int b = blockIdx.x;
    hist[t] = 0;
    __syncthreads();
    const int ebeg = binStart[b];
    const int eend = binStart[b + 1];
    for (int e = ebeg + t; e < eend; e += 256) atomicAdd(&hist[binned[e].y & 255], 1);
    __syncthreads();
    scn[t] = hist[t];
    __syncthreads();
    for (int off = 1; off < 256; off <<= 1) {
        const int x = (t >= off) ? scn[t - off] : 0;
        __syncthreads();
        scn[t] += x;
        __syncthreads();
    }
    const int node = b * 256 + t;
    if (node < N) rowptr[node] = ebeg + scn[t];
    curn[t] = ebeg + scn[t] - hist[t];
    __syncthreads();
    for (int e = ebeg + t; e < eend; e += 256) {
        const int2 v = binned[e];
        const int p = atomicAdd(&curn[v.y & 255], 1);
        epack[p] = v.x;
    }
}

// ---------------- CSR aggregate: one wave per node, bf16-hi gather ----------------
__global__ __launch_bounds__(256) void aggregate(
    const unsigned int* __restrict__ hu,
    const int* __restrict__ rowptr, const int* __restrict__ epack,
    const float* __restrict__ emb, float* __restrict__ agg, int N)
{
    const int node = blockIdx.x * 4 + (threadIdx.x >> 6);
    const int lane = threadIdx.x & 63;
    if (node >= N) return;

    int start = (node == 0) ? 0 : rowptr[node - 1];
    int end   = rowptr[node];
    start = __builtin_amdgcn_readfirstlane(start);
    end   = __builtin_amdgcn_readfirstlane(end);

    const float2* __restrict__ e2 = (const float2*)emb;

    float ax = 0.f, ay = 0.f;
    int j = start;
    for (; j + 3 < end; j += 4) {
        const int p0 = __builtin_amdgcn_readfirstlane(epack[j]);
        const int p1 = __builtin_amdgcn_readfirstlane(epack[j + 1]);
        const int p2 = __builtin_amdgcn_readfirstlane(epack[j + 2]);
        const int p3 = __builtin_amdgcn_readfirstlane(epack[j + 3]);
        const unsigned int u0 = hu[(p0 & 0xFFFFF) * 64 + lane];
        const unsigned int u1 = hu[(p1 & 0xFFFFF) * 64 + lane];
        const unsigned int u2 = hu[(p2 & 0xFFFFF) * 64 + lane];
        const unsigned int u3 = hu[(p3 & 0xFFFFF) * 64 + lane];
        const float2 e0 = e2[(p0 >> 20) * 64 + lane];
        const float2 e1 = e2[(p1 >> 20) * 64 + lane];
        const float2 ee2 = e2[(p2 >> 20) * 64 + lane];
        const float2 e3 = e2[(p3 >> 20) * 64 + lane];
        ax += fmaxf(__uint_as_float(u0 << 16) + e0.x, 0.f)
            + fmaxf(__uint_as_float(u1 << 16) + e1.x, 0.f)
            + fmaxf(__uint_as_float(u2 << 16) + ee2.x, 0.f)
            + fmaxf(__uint_as_float(u3 << 16) + e3.x, 0.f);
        ay += fmaxf(__uint_as_float(u0 & 0xffff0000u) + e0.y, 0.f)
            + fmaxf(__uint_as_float(u1 & 0xffff0000u) + e1.y, 0.f)
            + fmaxf(__uint_as_float(u2 & 0xffff0000u) + ee2.y, 0.f)
            + fmaxf(__uint_as_float(u3 & 0xffff0000u) + e3.y, 0.f);
    }
    for (; j < end; ++j) {
        const int p0 = __builtin_amdgcn_readfirstlane(epack[j]);
        const unsigned int u0 = hu[(p0 & 0xFFFFF) * 64 + lane];
        const float2 e0 = e2[(p0 >> 20) * 64 + lane];
        ax += fmaxf(__uint_as_float(u0 << 16) + e0.x, 0.f);
        ay += fmaxf(__uint_as_float(u0 & 0xffff0000u) + e0.y, 0.f);
    }
    float2 o; o.x = ax; o.y = ay;
    ((float2*)agg)[node * 64 + lane] = o;
}

// ---------------- output projection ----------------
__global__ __launch_bounds__(256) void out_proj(
    const float* __restrict__ h, const float* __restrict__ Wout,
    const float* __restrict__ bout, float* __restrict__ out, int N)
{
    const int gt = blockIdx.x * 256 + threadIdx.x;
    const int r = gt >> 2;
    if (r >= N) return;
    const int q = gt & 3;

    const float* hr = &h[r * D + q * 32];
    const float* wr = &Wout[q * 32];
    float acc = 0.f;
    #pragma unroll
    for (int k = 0; k < 32; k += 4) {
        const float4 hv = ld4(hr + k);
        const float4 wv = ld4(wr + k);
        acc += hv.x * wv.x + hv.y * wv.y + hv.z * wv.z + hv.w * wv.w;
    }
    acc += __shfl_xor(acc, 1);
    acc += __shfl_xor(acc, 2);
    if (q == 0) out[r] = acc + bout[0];
}

extern "C" void kernel_launch(void* const* d_in, const int* in_sizes, int n_in,
                              void* d_out, int out_size, void* d_ws, size_t ws_size,
                              hipStream_t stream)
{
    const float* x     = (const float*)d_in[0];
    const int*   ei    = (const int*)  d_in[1];
    const int*   attr  = (const int*)  d_in[2];
    const float* emb   = (const float*)d_in[3];
    const float* Win   = (const float*)d_in[4];
    const float* b_in  = (const float*)d_in[5];
    const float* W1_0  = (const float*)d_in[6];
    const float* b1_0  = (const float*)d_in[7];
    const float* W2_0  = (const float*)d_in[8];
    const float* b2_0  = (const float*)d_in[9];
    const float* W1_1  = (const float*)d_in[10];
    const float* b1_1  = (const float*)d_in[11];
    const float* W2_1  = (const float*)d_in[12];
    const float* b2_1  = (const float*)d_in[13];
    const float* Wout  = (const float*)d_in[14];
    const float* b_out = (const float*)d_in[15];
    float* out = (float*)d_out;

    const int N = NN;
    const int E = in_sizes[2];
    const int* srcp = ei;
    const int* dstp = ei + E;
    const int nbins = (N + 255) >> 8;
    const int eblocks = (E + CHUNK - 1) / CHUNK;

    // persistent workspace
    unsigned short* h_hi = (unsigned short*)d_ws;        // N*D ushort
    unsigned short* h_lo = h_hi + (size_t)N * D;         // N*D ushort
    float* agg    = (float*)(h_lo + (size_t)N * D);      // N*D float
    int*   rowptr = (int*)(agg + (size_t)N * D);         // N
    int*   epack  = rowptr + N;                          // E
    unsigned short* wp = (unsigned short*)(epack + E);   // 5*2*D*D
    unsigned short* Whi[5], *Wlo[5];
    for (int i = 0; i < 5; ++i) {
        Whi[i] = wp + (size_t)i * 2 * D * D;
        Wlo[i] = Whi[i] + D * D;
    }
    // CSR-build scratch aliased into agg (dead until first aggregate)
    int2* binned    = (int2*)agg;                         // E
    int*  blkcnt    = (int*)(binned + E);                 // eblocks*BCSTRIDE
    int*  binTotal  = blkcnt + eblocks * BCSTRIDE;        // nbins
    int*  binStart  = binTotal + BCSTRIDE;                // nbins+1
    int*  binCursor = binStart + BCSTRIDE;                // nbins

    dim3 blk(256);
    const int ggrid = (N + 127) / 128;
    const int fgrid = (N + 63) / 64;
    const int pgrid = (D * D + 255) / 256;

    // ---- W prepack ----
    prepack_w<<<pgrid, blk, 0, stream>>>(Win,  Whi[0], Wlo[0]);
    prepack_w<<<pgrid, blk, 0, stream>>>(W1_0, Whi[1], Wlo[1]);
    prepack_w<<<pgrid, blk, 0, stream>>>(W2_0, Whi[2], Wlo[2]);
    prepack_w<<<pgrid, blk, 0, stream>>>(W1_1, Whi[3], Wlo[3]);
    prepack_w<<<pgrid, blk, 0, stream>>>(W2_1, Whi[4], Wlo[4]);

    // ---- binned CSR build ----
    hipMemsetAsync(binTotal, 0, BCSTRIDE * sizeof(int), stream);
    bin_count<<<eblocks, blk, 0, stream>>>(dstp, blkcnt, binTotal, E, nbins);
    bin_scan<<<1, 512, 0, stream>>>(binTotal, binStart, binCursor, nbins);
    bin_scatter<<<eblocks, blk, 0, stream>>>(srcp, dstp, attr, blkcnt, binCursor, binned, E, nbins);
    bin_build<<<nbins, blk, 0, stream>>>(binned, binStart, rowptr, epack, N);

    // ---- h = x @ Win + b_in  (write split h) ----
    gemm_in<<<ggrid, blk, 0, stream>>>(x, Whi[0], Wlo[0], b_in, h_hi, h_lo, N);

    // ---- layer 0 ----
    aggregate<<<(N + 3) / 4, blk, 0, stream>>>(
        (const unsigned int*)h_hi, rowptr, epack, emb, agg, N);
    mlp_fused<false><<<fgrid, dim3(128), 0, stream>>>(
        agg, h_hi, h_lo, Whi[1], Wlo[1], b1_0, Whi[2], Wlo[2], b2_0,
        h_hi, h_lo, nullptr, N);

    // ---- layer 1 (final h -> fp32 agg for out_proj) ----
    aggregate<<<(N + 3) / 4, blk, 0, stream>>>(
        (const unsigned int*)h_hi, rowptr, epack, emb, agg, N);
    mlp_fused<true><<<fgrid, dim3(128), 0, stream>>>(
        agg, h_hi, h_lo, Whi[3], Wlo[3], b1_1, Whi[4], Wlo[4], b2_1,
        nullptr, nullptr, agg, N);

    out_proj<<<(N * 4 + 255) / 256, blk, 0, stream>>>(agg, Wout, b_out, out, N);
}

// Round 10
// 506.680 us; speedup vs baseline: 11.5703x; 1.2653x over previous
//
#include <hip/hip_runtime.h>

#define NN 100000
#define D 128
#define CHUNK 4096
#define BCSTRIDE 392

typedef __attribute__((ext_vector_type(8))) short short8;
typedef __attribute__((ext_vector_type(8))) unsigned short ushort8;
typedef __attribute__((ext_vector_type(4))) float f32x4;

__device__ __forceinline__ float4 ld4(const float* p) { return *(const float4*)p; }

__device__ __forceinline__ unsigned short f2bf(float f) {
    unsigned int u = __float_as_uint(f);
    unsigned int r = u + 0x7fffu + ((u >> 16) & 1u);   // RNE
    return (unsigned short)(r >> 16);
}
__device__ __forceinline__ float bf2f(unsigned short h) {
    return __uint_as_float(((unsigned int)h) << 16);
}

// ---------------- W prepack: fragment-ordered hi/lo bf16 ----------------
__global__ __launch_bounds__(256) void prepack_w(
    const float* __restrict__ W, unsigned short* __restrict__ hi,
    unsigned short* __restrict__ lo)
{
    const int t = blockIdx.x * 256 + threadIdx.x;
    if (t >= D * D) return;
    const int j  = t & 7;
    const int L  = (t >> 3) & 63;
    const int ks = (t >> 9) & 3;
    const int nt = t >> 11;
    const float v = W[(ks * 32 + (L >> 4) * 8 + j) * D + nt * 16 + (L & 15)];
    const unsigned short h = f2bf(v);
    hi[t] = h;
    lo[t] = f2bf(v - bf2f(h));
}

// ---------------- input GEMM: h(split) = x @ Win + b_in ----------------
// 256 thr / 4 waves / 64 rows (16 rows per wave); vector epilogue via LDS.
__global__ __launch_bounds__(256) void gemm_in(
    const float* __restrict__ A1,
    const unsigned short* __restrict__ Whi, const unsigned short* __restrict__ Wlo,
    const float* __restrict__ bias,
    unsigned short* __restrict__ out_hi, unsigned short* __restrict__ out_lo, int N)
{
    __shared__ unsigned int uT[64 * 132];
    const int t  = threadIdx.x;
    const int wv = t >> 6;
    const int L  = t & 63;
    const int lr = L & 15;
    const int q  = L >> 4;
    const int rbase = wv * 16;
    const int row = blockIdx.x * 64 + rbase + lr;   // A-layout row for this thread

    // stage: load x (A-layout), split to hi/lo
    short8 ahi[4], alo[4];
    #pragma unroll
    for (int ks = 0; ks < 4; ++ks) {
        float v[8];
        if (row < N) {
            const int off = row * D + ks * 32 + q * 8;
            const float4 x0 = ld4(&A1[off]), x1 = ld4(&A1[off + 4]);
            v[0] = x0.x; v[1] = x0.y; v[2] = x0.z; v[3] = x0.w;
            v[4] = x1.x; v[5] = x1.y; v[6] = x1.z; v[7] = x1.w;
        } else {
            #pragma unroll
            for (int j = 0; j < 8; ++j) v[j] = 0.f;
        }
        #pragma unroll
        for (int j = 0; j < 8; ++j) {
            const unsigned short h = f2bf(v[j]);
            ahi[ks][j] = (short)h;
            alo[ks][j] = (short)f2bf(v[j] - bf2f(h));
        }
    }

    f32x4 acc[8];
    #pragma unroll
    for (int nt = 0; nt < 8; ++nt) acc[nt] = (f32x4){0.f, 0.f, 0.f, 0.f};

    #pragma unroll
    for (int ks = 0; ks < 4; ++ks)
        #pragma unroll
        for (int nt = 0; nt < 8; ++nt) {
            const int base = ((nt * 4 + ks) * 64 + L) * 8;
            const short8 bhi = *(const short8*)&Whi[base];
            const short8 blo = *(const short8*)&Wlo[base];
            acc[nt] = __builtin_amdgcn_mfma_f32_16x16x32_bf16(alo[ks], bhi, acc[nt], 0, 0, 0);
            acc[nt] = __builtin_amdgcn_mfma_f32_16x16x32_bf16(ahi[ks], blo, acc[nt], 0, 0, 0);
            acc[nt] = __builtin_amdgcn_mfma_f32_16x16x32_bf16(ahi[ks], bhi, acc[nt], 0, 0, 0);
        }

    // C-layout -> LDS (fp32 bits), then A-layout vector stores
    #pragma unroll
    for (int nt = 0; nt < 8; ++nt) {
        const float b = bias[nt * 16 + lr];
        #pragma unroll
        for (int r = 0; r < 4; ++r) {
            const int rloc = rbase + q * 4 + r;
            uT[rloc * 132 + nt * 16 + lr] = __float_as_uint(acc[nt][r] + b);
        }
    }
    __syncthreads();
    if (row < N) {
        #pragma unroll
        for (int ks = 0; ks < 4; ++ks) {
            const unsigned int* p = &uT[(rbase + lr) * 132 + ks * 32 + q * 8];
            const int off = row * D + ks * 32 + q * 8;
            ushort8 oh, ol;
            #pragma unroll
            for (int j = 0; j < 8; ++j) {
                const float o = __uint_as_float(p[j]);
                const unsigned short h = f2bf(o);
                oh[j] = h;
                ol[j] = f2bf(o - bf2f(h));
            }
            *(ushort8*)&out_hi[off] = oh;
            *(ushort8*)&out_lo[off] = ol;
        }
    }
}

// ---------------- fused GINE MLP: u=relu((agg+h)W1+b1); h'=relu(uW2+b2+h) ----------------
// 256 thr / 4 waves / 64 rows (16 per wave); u + epilogue transposes in LDS;
// residual reuses stage-1 hh/ll registers (A-layout rows/cols identical).
template<bool LAST>
__global__ __launch_bounds__(256) void mlp_fused(
    const float* __restrict__ agg,
    const unsigned short* __restrict__ h_hi, const unsigned short* __restrict__ h_lo,
    const unsigned short* __restrict__ W1hi, const unsigned short* __restrict__ W1lo,
    const float* __restrict__ b1,
    const unsigned short* __restrict__ W2hi, const unsigned short* __restrict__ W2lo,
    const float* __restrict__ b2,
    unsigned short* __restrict__ out_hi, unsigned short* __restrict__ out_lo,
    float* __restrict__ out_f, int N)
{
    __shared__ unsigned int uT[64 * 132];
    const int t  = threadIdx.x;
    const int wv = t >> 6;
    const int L  = t & 63;
    const int lr = L & 15;
    const int q  = L >> 4;
    const int rbase = wv * 16;
    const int row = blockIdx.x * 64 + rbase + lr;

    // ---- stage 1 loads: agg (fp32) + h (split); keep hh/ll for residual ----
    ushort8 hh[4], ll[4];
    short8 ahi[4], alo[4];
    #pragma unroll
    for (int ks = 0; ks < 4; ++ks) {
        float v[8];
        if (row < N) {
            const int off = row * D + ks * 32 + q * 8;
            const float4 x0 = ld4(&agg[off]), x1 = ld4(&agg[off + 4]);
            hh[ks] = *(const ushort8*)&h_hi[off];
            ll[ks] = *(const ushort8*)&h_lo[off];
            v[0] = x0.x; v[1] = x0.y; v[2] = x0.z; v[3] = x0.w;
            v[4] = x1.x; v[5] = x1.y; v[6] = x1.z; v[7] = x1.w;
        } else {
            hh[ks] = (ushort8)0; ll[ks] = (ushort8)0;
            #pragma unroll
            for (int j = 0; j < 8; ++j) v[j] = 0.f;
        }
        #pragma unroll
        for (int j = 0; j < 8; ++j) {
            v[j] += bf2f(hh[ks][j]) + bf2f(ll[ks][j]);
            const unsigned short h = f2bf(v[j]);
            ahi[ks][j] = (short)h;
            alo[ks][j] = (short)f2bf(v[j] - bf2f(h));
        }
    }

    f32x4 acc[8];
    #pragma unroll
    for (int nt = 0; nt < 8; ++nt) acc[nt] = (f32x4){0.f, 0.f, 0.f, 0.f};

    #pragma unroll
    for (int ks = 0; ks < 4; ++ks)
        #pragma unroll
        for (int nt = 0; nt < 8; ++nt) {
            const int base = ((nt * 4 + ks) * 64 + L) * 8;
            const short8 bhi = *(const short8*)&W1hi[base];
            const short8 blo = *(const short8*)&W1lo[base];
            acc[nt] = __builtin_amdgcn_mfma_f32_16x16x32_bf16(alo[ks], bhi, acc[nt], 0, 0, 0);
            acc[nt] = __builtin_amdgcn_mfma_f32_16x16x32_bf16(ahi[ks], blo, acc[nt], 0, 0, 0);
            acc[nt] = __builtin_amdgcn_mfma_f32_16x16x32_bf16(ahi[ks], bhi, acc[nt], 0, 0, 0);
        }

    // u = relu(acc + b1) -> LDS packed hi|lo (C-layout)
    #pragma unroll
    for (int nt = 0; nt < 8; ++nt) {
        const float b = b1[nt * 16 + lr];
        #pragma unroll
        for (int r = 0; r < 4; ++r) {
            const int rloc = rbase + q * 4 + r;
            const float o = fmaxf(acc[nt][r] + b, 0.f);
            const unsigned int hi = f2bf(o);
            const unsigned int lo = f2bf(o - bf2f((unsigned short)hi));
            uT[rloc * 132 + nt * 16 + lr] = (hi << 16) | lo;
        }
    }
    __syncthreads();

    // ---- stage 2: u from LDS (A-layout) ----
    short8 uhi[4], ulo[4];
    #pragma unroll
    for (int ks = 0; ks < 4; ++ks) {
        const unsigned int* p = &uT[(rbase + lr) * 132 + ks * 32 + q * 8];
        #pragma unroll
        for (int j = 0; j < 8; ++j) {
            const unsigned int v = p[j];
            uhi[ks][j] = (short)(v >> 16);
            ulo[ks][j] = (short)(v & 0xffffu);
        }
    }

    f32x4 acc2[8];
    #pragma unroll
    for (int nt = 0; nt < 8; ++nt) acc2[nt] = (f32x4){0.f, 0.f, 0.f, 0.f};

    #pragma unroll
    for (int ks = 0; ks < 4; ++ks)
        #pragma unroll
        for (int nt = 0; nt < 8; ++nt) {
            const int base = ((nt * 4 + ks) * 64 + L) * 8;
            const short8 bhi = *(const short8*)&W2hi[base];
            const short8 blo = *(const short8*)&W2lo[base];
            acc2[nt] = __builtin_amdgcn_mfma_f32_16x16x32_bf16(ulo[ks], bhi, acc2[nt], 0, 0, 0);
            acc2[nt] = __builtin_amdgcn_mfma_f32_16x16x32_bf16(uhi[ks], blo, acc2[nt], 0, 0, 0);
            acc2[nt] = __builtin_amdgcn_mfma_f32_16x16x32_bf16(uhi[ks], bhi, acc2[nt], 0, 0, 0);
        }
    __syncthreads();   // all stage-2 LDS reads done before reuse

    // acc2 + b2 -> LDS (fp32 bits, C-layout)
    #pragma unroll
    for (int nt = 0; nt < 8; ++nt) {
        const float b = b2[nt * 16 + lr];
        #pragma unroll
        for (int r = 0; r < 4; ++r) {
            const int rloc = rbase + q * 4 + r;
            uT[rloc * 132 + nt * 16 + lr] = __float_as_uint(acc2[nt][r] + b);
        }
    }
    __syncthreads();

    // A-layout epilogue: + residual (register hh/ll), relu, vector store
    if (row < N) {
        #pragma unroll
        for (int ks = 0; ks < 4; ++ks) {
            const unsigned int* p = &uT[(rbase + lr) * 132 + ks * 32 + q * 8];
            const int off = row * D + ks * 32 + q * 8;
            float o[8];
            #pragma unroll
            for (int j = 0; j < 8; ++j)
                o[j] = fmaxf(__uint_as_float(p[j]) + bf2f(hh[ks][j]) + bf2f(ll[ks][j]), 0.f);
            if (LAST) {
                *(float4*)&out_f[off]     = make_float4(o[0], o[1], o[2], o[3]);
                *(float4*)&out_f[off + 4] = make_float4(o[4], o[5], o[6], o[7]);
            } else {
                ushort8 oh, ol;
                #pragma unroll
                for (int j = 0; j < 8; ++j) {
                    const unsigned short h = f2bf(o[j]);
                    oh[j] = h;
                    ol[j] = f2bf(o[j] - bf2f(h));
                }
                *(ushort8*)&out_hi[off] = oh;
                *(ushort8*)&out_lo[off] = ol;
            }
        }
    }
}

// ---------------- binned CSR build ----------------
__global__ __launch_bounds__(256) void bin_count(
    const int* __restrict__ dst, int* __restrict__ blkcnt,
    int* __restrict__ binTotal, int E, int nbins)
{
    __shared__ int hist[512];
    const int t = threadIdx.x;
    const int i = blockIdx.x;
    for (int k = t; k < nbins; k += 256) hist[k] = 0;
    __syncthreads();
    const int e0 = i * CHUNK;
    const int e1 = min(E, e0 + CHUNK);
    for (int e = e0 + t; e < e1; e += 256) atomicAdd(&hist[dst[e] >> 8], 1);
    __syncthreads();
    for (int k = t; k < nbins; k += 256) {
        const int c = hist[k];
        blkcnt[i * BCSTRIDE + k] = c;
        if (c) atomicAdd(&binTotal[k], c);
    }
}

__global__ __launch_bounds__(512) void bin_scan(
    const int* __restrict__ binTotal, int* __restrict__ binStart,
    int* __restrict__ binCursor, int nbins)
{
    __shared__ int s[512];
    const int t = threadIdx.x;
    const int v = (t < nbins) ? binTotal[t] : 0;
    s[t] = v;
    __syncthreads();
    for (int off = 1; off < 512; off <<= 1) {
        const int x = (t >= off) ? s[t - off] : 0;
        __syncthreads();
        s[t] += x;
        __syncthreads();
    }
    if (t < nbins) { binStart[t] = s[t] - v; binCursor[t] = s[t] - v; }
    if (t == 0)    binStart[nbins] = s[511];
}

__global__ __launch_bounds__(256) void bin_scatter(
    const int* __restrict__ src, const int* __restrict__ dst,
    const int* __restrict__ attr, const int* __restrict__ blkcnt,
    int* __restrict__ binCursor, int2* __restrict__ binned, int E, int nbins)
{
    __shared__ int cur[512];
    const int t = threadIdx.x;
    const int i = blockIdx.x;
    for (int k = t; k < nbins; k += 256) {
        const int c = blkcnt[i * BCSTRIDE + k];
        if (c) cur[k] = atomicAdd(&binCursor[k], c);
    }
    __syncthreads();
    const int e0 = i * CHUNK;
    const int e1 = min(E, e0 + CHUNK);
    for (int e = e0 + t; e < e1; e += 256) {
        const int d = dst[e];
        const int p = atomicAdd(&cur[d >> 8], 1);
        binned[p] = make_int2(src[e] | (attr[e] << 20), d);
    }
}

__global__ __launch_bounds__(256) void bin_build(
    const int2* __restrict__ binned, const int* __restrict__ binStart,
    int* __restrict__ rowptr, int* __restrict__ epack, int N)
{
    __shared__ int hist[256];
    __shared__ int scn[256];
    __shared__ int curn[256];
    const int t = threadIdx.x;
    const int b = blockIdx.x;
    hist[t] = 0;
    __syncthreads();
    const int ebeg = binStart[b];
    const int eend = binStart[b + 1];
    for (int e = ebeg + t; e < eend; e += 256) atomicAdd(&hist[binned[e].y & 255], 1);
    __syncthreads();
    scn[t] = hist[t];
    __syncthreads();
    for (int off = 1; off < 256; off <<= 1) {
        const int x = (t >= off) ? scn[t - off] : 0;
        __syncthreads();
        scn[t] += x;
        __syncthreads();
    }
    const int node = b * 256 + t;
    if (node < N) rowptr[node] = ebeg + scn[t];
    curn[t] = ebeg + scn[t] - hist[t];
    __syncthreads();
    for (int e = ebeg + t; e < eend; e += 256) {
        const int2 v = binned[e];
        const int p = atomicAdd(&curn[v.y & 255], 1);
        epack[p] = v.x;
    }
}

// ---------------- CSR aggregate: one wave per node, bf16-hi gather ----------------
__global__ __launch_bounds__(256) void aggregate(
    const unsigned int* __restrict__ hu,
    const int* __restrict__ rowptr, const int* __restrict__ epack,
    const float* __restrict__ emb, float* __restrict__ agg, int N)
{
    const int node = blockIdx.x * 4 + (threadIdx.x >> 6);
    const int lane = threadIdx.x & 63;
    if (node >= N) return;

    int start = (node == 0) ? 0 : rowptr[node - 1];
    int end   = rowptr[node];
    start = __builtin_amdgcn_readfirstlane(start);
    end   = __builtin_amdgcn_readfirstlane(end);

    const float2* __restrict__ e2 = (const float2*)emb;

    float ax = 0.f, ay = 0.f;
    int j = start;
    for (; j + 3 < end; j += 4) {
        const int p0 = __builtin_amdgcn_readfirstlane(epack[j]);
        const int p1 = __builtin_amdgcn_readfirstlane(epack[j + 1]);
        const int p2 = __builtin_amdgcn_readfirstlane(epack[j + 2]);
        const int p3 = __builtin_amdgcn_readfirstlane(epack[j + 3]);
        const unsigned int u0 = hu[(p0 & 0xFFFFF) * 64 + lane];
        const unsigned int u1 = hu[(p1 & 0xFFFFF) * 64 + lane];
        const unsigned int u2 = hu[(p2 & 0xFFFFF) * 64 + lane];
        const unsigned int u3 = hu[(p3 & 0xFFFFF) * 64 + lane];
        const float2 e0 = e2[(p0 >> 20) * 64 + lane];
        const float2 e1 = e2[(p1 >> 20) * 64 + lane];
        const float2 ee2 = e2[(p2 >> 20) * 64 + lane];
        const float2 e3 = e2[(p3 >> 20) * 64 + lane];
        ax += fmaxf(__uint_as_float(u0 << 16) + e0.x, 0.f)
            + fmaxf(__uint_as_float(u1 << 16) + e1.x, 0.f)
            + fmaxf(__uint_as_float(u2 << 16) + ee2.x, 0.f)
            + fmaxf(__uint_as_float(u3 << 16) + e3.x, 0.f);
        ay += fmaxf(__uint_as_float(u0 & 0xffff0000u) + e0.y, 0.f)
            + fmaxf(__uint_as_float(u1 & 0xffff0000u) + e1.y, 0.f)
            + fmaxf(__uint_as_float(u2 & 0xffff0000u) + ee2.y, 0.f)
            + fmaxf(__uint_as_float(u3 & 0xffff0000u) + e3.y, 0.f);
    }
    for (; j < end; ++j) {
        const int p0 = __builtin_amdgcn_readfirstlane(epack[j]);
        const unsigned int u0 = hu[(p0 & 0xFFFFF) * 64 + lane];
        const float2 e0 = e2[(p0 >> 20) * 64 + lane];
        ax += fmaxf(__uint_as_float(u0 << 16) + e0.x, 0.f);
        ay += fmaxf(__uint_as_float(u0 & 0xffff0000u) + e0.y, 0.f);
    }
    float2 o; o.x = ax; o.y = ay;
    ((float2*)agg)[node * 64 + lane] = o;
}

// ---------------- output projection ----------------
__global__ __launch_bounds__(256) void out_proj(
    const float* __restrict__ h, const float* __restrict__ Wout,
    const float* __restrict__ bout, float* __restrict__ out, int N)
{
    const int gt = blockIdx.x * 256 + threadIdx.x;
    const int r = gt >> 2;
    if (r >= N) return;
    const int q = gt & 3;

    const float* hr = &h[r * D + q * 32];
    const float* wr = &Wout[q * 32];
    float acc = 0.f;
    #pragma unroll
    for (int k = 0; k < 32; k += 4) {
        const float4 hv = ld4(hr + k);
        const float4 wv = ld4(wr + k);
        acc += hv.x * wv.x + hv.y * wv.y + hv.z * wv.z + hv.w * wv.w;
    }
    acc += __shfl_xor(acc, 1);
    acc += __shfl_xor(acc, 2);
    if (q == 0) out[r] = acc + bout[0];
}

extern "C" void kernel_launch(void* const* d_in, const int* in_sizes, int n_in,
                              void* d_out, int out_size, void* d_ws, size_t ws_size,
                              hipStream_t stream)
{
    const float* x     = (const float*)d_in[0];
    const int*   ei    = (const int*)  d_in[1];
    const int*   attr  = (const int*)  d_in[2];
    const float* emb   = (const float*)d_in[3];
    const float* Win   = (const float*)d_in[4];
    const float* b_in  = (const float*)d_in[5];
    const float* W1_0  = (const float*)d_in[6];
    const float* b1_0  = (const float*)d_in[7];
    const float* W2_0  = (const float*)d_in[8];
    const float* b2_0  = (const float*)d_in[9];
    const float* W1_1  = (const float*)d_in[10];
    const float* b1_1  = (const float*)d_in[11];
    const float* W2_1  = (const float*)d_in[12];
    const float* b2_1  = (const float*)d_in[13];
    const float* Wout  = (const float*)d_in[14];
    const float* b_out = (const float*)d_in[15];
    float* out = (float*)d_out;

    const int N = NN;
    const int E = in_sizes[2];
    const int* srcp = ei;
    const int* dstp = ei + E;
    const int nbins = (N + 255) >> 8;
    const int eblocks = (E + CHUNK - 1) / CHUNK;

    // persistent workspace
    unsigned short* h_hi = (unsigned short*)d_ws;        // N*D ushort
    unsigned short* h_lo = h_hi + (size_t)N * D;         // N*D ushort
    float* agg    = (float*)(h_lo + (size_t)N * D);      // N*D float
    int*   rowptr = (int*)(agg + (size_t)N * D);         // N
    int*   epack  = rowptr + N;                          // E
    unsigned short* wp = (unsigned short*)(epack + E);   // 5*2*D*D
    unsigned short* Whi[5], *Wlo[5];
    for (int i = 0; i < 5; ++i) {
        Whi[i] = wp + (size_t)i * 2 * D * D;
        Wlo[i] = Whi[i] + D * D;
    }
    // CSR-build scratch aliased into agg (dead until first aggregate)
    int2* binned    = (int2*)agg;                         // E
    int*  blkcnt    = (int*)(binned + E);                 // eblocks*BCSTRIDE
    int*  binTotal  = blkcnt + eblocks * BCSTRIDE;        // nbins
    int*  binStart  = binTotal + BCSTRIDE;                // nbins+1
    int*  binCursor = binStart + BCSTRIDE;                // nbins

    dim3 blk(256);
    const int fgrid = (N + 63) / 64;
    const int pgrid = (D * D + 255) / 256;

    // ---- W prepack ----
    prepack_w<<<pgrid, blk, 0, stream>>>(Win,  Whi[0], Wlo[0]);
    prepack_w<<<pgrid, blk, 0, stream>>>(W1_0, Whi[1], Wlo[1]);
    prepack_w<<<pgrid, blk, 0, stream>>>(W2_0, Whi[2], Wlo[2]);
    prepack_w<<<pgrid, blk, 0, stream>>>(W1_1, Whi[3], Wlo[3]);
    prepack_w<<<pgrid, blk, 0, stream>>>(W2_1, Whi[4], Wlo[4]);

    // ---- binned CSR build ----
    hipMemsetAsync(binTotal, 0, BCSTRIDE * sizeof(int), stream);
    bin_count<<<eblocks, blk, 0, stream>>>(dstp, blkcnt, binTotal, E, nbins);
    bin_scan<<<1, 512, 0, stream>>>(binTotal, binStart, binCursor, nbins);
    bin_scatter<<<eblocks, blk, 0, stream>>>(srcp, dstp, attr, blkcnt, binCursor, binned, E, nbins);
    bin_build<<<nbins, blk, 0, stream>>>(binned, binStart, rowptr, epack, N);

    // ---- h = x @ Win + b_in  (write split h) ----
    gemm_in<<<fgrid, blk, 0, stream>>>(x, Whi[0], Wlo[0], b_in, h_hi, h_lo, N);

    // ---- layer 0 ----
    aggregate<<<(N + 3) / 4, blk, 0, stream>>>(
        (const unsigned int*)h_hi, rowptr, epack, emb, agg, N);
    mlp_fused<false><<<fgrid, blk, 0, stream>>>(
        agg, h_hi, h_lo, Whi[1], Wlo[1], b1_0, Whi[2], Wlo[2], b2_0,
        h_hi, h_lo, nullptr, N);

    // ---- layer 1 (final h -> fp32 agg for out_proj) ----
    aggregate<<<(N + 3) / 4, blk, 0, stream>>>(
        (const unsigned int*)h_hi, rowptr, epack, emb, agg, N);
    mlp_fused<true><<<fgrid, blk, 0, stream>>>(
        agg, h_hi, h_lo, Whi[3], Wlo[3], b1_1, Whi[4], Wlo[4], b2_1,
        nullptr, nullptr, agg, N);

    out_proj<<<(N * 4 + 255) / 256, blk, 0, stream>>>(agg, Wout, b_out, out, N);
}